// Round 9
// baseline (914.537 us; speedup 1.0000x reference)
//
#include <hip/hip_runtime.h>
#include <stdint.h>

typedef __attribute__((ext_vector_type(4))) float f32x4;
typedef __attribute__((ext_vector_type(8))) short bf16x8;

__device__ __forceinline__ float bitsf(unsigned u) {
  union { unsigned u; float f; } x; x.u = u; return x.f;
}
__device__ __forceinline__ float b2f(unsigned short u) { return bitsf(((unsigned)u) << 16); }
__device__ __forceinline__ unsigned short f2b(float f) {
  union { float f; unsigned u; } x; x.f = f;
  unsigned r = x.u + 0x7FFFu + ((x.u >> 16) & 1u);
  return (unsigned short)(r >> 16);
}
__device__ __forceinline__ unsigned pack2(float lo, float hi) {
  return ((unsigned)f2b(hi) << 16) | f2b(lo);
}
__device__ __forceinline__ void async16(const void* g, void* l) {
  __builtin_amdgcn_global_load_lds((const __attribute__((address_space(1))) unsigned*)g,
                                   (__attribute__((address_space(3))) unsigned*)l, 16, 0, 0);
}
__device__ __forceinline__ void unpack8(uint4 u, float* f) {
  f[0] = bitsf(u.x << 16); f[1] = bitsf(u.x & 0xFFFF0000u);
  f[2] = bitsf(u.y << 16); f[3] = bitsf(u.y & 0xFFFF0000u);
  f[4] = bitsf(u.z << 16); f[5] = bitsf(u.z & 0xFFFF0000u);
  f[6] = bitsf(u.w << 16); f[7] = bitsf(u.w & 0xFFFF0000u);
}

// out[m,n] = relu?(acc+bias) (+residb); A: MxK bf16 rm, B: NnxK bf16 rm.
// v6 = round-5 BK=32 geometry (conflict-free B row-permuted layout, PASSED on
// HW) + T4 counted-vmcnt pipeline: 3-buffer ring, 2-ahead prefetch, raw
// s_barrier. Per iter: issue tile t+2 (4 loads) -> compute tile t ->
// s_waitcnt vmcnt(4) (tile t+1 landed, t+2 still in flight) -> s_barrier.
// Unlike __syncthreads() (unconditional vmcnt(0) drain, the m97 stall), the
// prefetch survives the barrier. LDS 3x16KB=48KB -> 3 blocks/CU.
// Layout (round-5, verified): A LDS rows = global rows, slot swizzle
// sigma(r)=(r>>1)&3. B staging permutes rows: LDS row 32w+16c+rloc holds
// global row n0+64*(w>>1)+4*rloc+2*(w&1)+c, so read row wn+ni*16+lr gives
// fragment ni = global col n0+wn+4*lr+ni => packed uint2 epilogue; read
// bank pattern identical to A (conflict-free).
// Race discipline: every wait has "memory" clobber (also pins epilogue loads
// out of the loop's vmcnt FIFO window); sched_barrier(0) after each barrier
// stops LDS-read hoisting; buffer WAR separated by 2 barriers.
__global__ __launch_bounds__(256, 3) void gemm_bt(
    const unsigned short* __restrict__ A, const unsigned short* __restrict__ B,
    const float* __restrict__ bias, int relu,
    const unsigned short* __restrict__ residb,
    unsigned short* __restrict__ outb,
    float* __restrict__ bns, int statN,
    int Nn, int K, int YT, int XCHUNK)
{
  __shared__ __attribute__((aligned(16))) unsigned short As[3 * 128 * 32];
  __shared__ __attribute__((aligned(16))) unsigned short Bs[3 * 128 * 32];
  const int b = blockIdx.x;
  const int slot = b >> 3;
  const int m0 = ((b & 7) * XCHUNK + slot / YT) * 128;
  const int n0 = (slot % YT) * 128;
  const int tid = threadIdx.x;
  const int lane = tid & 63;
  const int wave = tid >> 6;
  const int wm = (wave & 1) * 64, wn = (wave >> 1) * 64;
  const int lr = lane & 15, lq = lane >> 4;

  f32x4 acc[4][4];
#pragma unroll
  for (int i = 0; i < 4; i++)
#pragma unroll
    for (int j = 0; j < 4; j++) acc[i][j] = (f32x4){0.f, 0.f, 0.f, 0.f};

  // staging (round-5 BK=32): wave w owns LDS rows 32w..32w+31, 2 calls of 16.
  // lane i -> row rloc=i>>2, slot i&2bits; slot swizzle sigma(r)=(r>>1)&3.
  const int rloc = lane >> 2;                 // 0..15
  const int sl = lane & 3;
  const int gsw = sl ^ ((rloc >> 1) & 3);
  const int rA0 = 32 * wave + rloc, rA1 = rA0 + 16;
  const unsigned short* gA0 = A + (size_t)(m0 + rA0) * K + gsw * 8;
  const unsigned short* gA1 = A + (size_t)(m0 + rA1) * K + gsw * 8;
  // B row permutation: LDS row 32w+16c+rloc <- global row n0+64*(w>>1)+4*rloc+2*(w&1)+c
  const int brow = n0 + 64 * (wave >> 1) + 4 * rloc + 2 * (wave & 1);
  const unsigned short* gB0 = B + (size_t)brow * K + gsw * 8;
  const unsigned short* gB1 = B + (size_t)(brow + 1) * K + gsw * 8;
  const int pos8 = (lq ^ ((lr >> 1) & 3)) << 3;  // read slot -> k-block lq

  const int T = K >> 5;  // number of 32-wide K-tiles (>=16 for all call sites)
  char* const lA0 = (char*)As + wave * 2048;  // wave-uniform; HW adds lane*16
  char* const lB0 = (char*)Bs + wave * 2048;

  // prologue: stage tiles 0,1 into bufs 0,1 (8 loads in flight)
  {
    async16(gA0, lA0);       async16(gA1, lA0 + 1024);
    async16(gB0, lB0);       async16(gB1, lB0 + 1024);
    async16(gA0 + 32, lA0 + 8192); async16(gA1 + 32, lA0 + 8192 + 1024);
    async16(gB0 + 32, lB0 + 8192); async16(gB1 + 32, lB0 + 8192 + 1024);
  }
  asm volatile("s_waitcnt vmcnt(4)" ::: "memory");  // tile 0 landed
  __builtin_amdgcn_s_barrier();
  __builtin_amdgcn_sched_barrier(0);

  int bcur = 0;
  for (int t = 0; t < T; t++) {
    if (t + 2 < T) {  // stage tile t+2 into buf (t+2)%3 (overlaps compute)
      int bn = bcur + 2; if (bn >= 3) bn -= 3;
      const int k0 = (t + 2) << 5;
      char* nA = lA0 + bn * 8192;
      char* nB = lB0 + bn * 8192;
      async16(gA0 + k0, nA); async16(gA1 + k0, nA + 1024);
      async16(gB0 + k0, nB); async16(gB1 + k0, nB + 1024);
    }
    const unsigned short* cA = As + bcur * 4096;
    const unsigned short* cB = Bs + bcur * 4096;
    bf16x8 af[4], bfr[4];
#pragma unroll
    for (int mi = 0; mi < 4; mi++)
      af[mi] = *(const bf16x8*)&cA[(wm + mi * 16 + lr) * 32 + pos8];
#pragma unroll
    for (int ni = 0; ni < 4; ni++)
      bfr[ni] = *(const bf16x8*)&cB[(wn + ni * 16 + lr) * 32 + pos8];
#pragma unroll
    for (int mi = 0; mi < 4; mi++)
#pragma unroll
      for (int ni = 0; ni < 4; ni++)
        acc[mi][ni] = __builtin_amdgcn_mfma_f32_16x16x32_bf16(af[mi], bfr[ni], acc[mi][ni], 0, 0, 0);
    // counted drain: tile t+1 must be landed before next iter reads it;
    // tile t+2 (4 newest loads) stays in flight across the barrier.
    if (t + 2 < T) {
      asm volatile("s_waitcnt vmcnt(4)" ::: "memory");
    } else if (t + 1 < T) {
      asm volatile("s_waitcnt vmcnt(0)" ::: "memory");
    }
    __builtin_amdgcn_s_barrier();
    __builtin_amdgcn_sched_barrier(0);
    bcur++; if (bcur >= 3) bcur = 0;
  }

  // D elem: m = wm+mi*16+lq*4+r, n = wn+lr*4+ni (B row permutation => consecutive n)
  float sn[4] = {0, 0, 0, 0}, qn[4] = {0, 0, 0, 0};
  const int gnb = n0 + wn + lr * 4;
  float4 bv = {0.f, 0.f, 0.f, 0.f};
  if (bias) bv = *(const float4*)&bias[gnb];
#pragma unroll
  for (int mi = 0; mi < 4; mi++) {
#pragma unroll
    for (int r = 0; r < 4; r++) {
      int gm = m0 + wm + mi * 16 + lq * 4 + r;
      size_t base = (size_t)gm * Nn + gnb;
      float v0 = acc[mi][0][r] + bv.x;
      float v1 = acc[mi][1][r] + bv.y;
      float v2 = acc[mi][2][r] + bv.z;
      float v3 = acc[mi][3][r] + bv.w;
      if (relu) {
        v0 = fmaxf(v0, 0.f); v1 = fmaxf(v1, 0.f);
        v2 = fmaxf(v2, 0.f); v3 = fmaxf(v3, 0.f);
      }
      if (residb) {
        uint2 rb = *(const uint2*)&residb[base];
        v0 += bitsf(rb.x << 16); v1 += bitsf(rb.x & 0xFFFF0000u);
        v2 += bitsf(rb.y << 16); v3 += bitsf(rb.y & 0xFFFF0000u);
      }
      uint2 o;
      o.x = pack2(v0, v1);
      o.y = pack2(v2, v3);
      *(uint2*)&outb[base] = o;
      if (bns && gm < statN) {
        sn[0] += v0; qn[0] += v0 * v0;
        sn[1] += v1; qn[1] += v1 * v1;
        sn[2] += v2; qn[2] += v2 * v2;
        sn[3] += v3; qn[3] += v3 * v3;
      }
    }
  }
  if (bns) {
#pragma unroll
    for (int ni = 0; ni < 4; ni++) {
      float s = sn[ni], q = qn[ni];
      s += __shfl_xor(s, 16, 64); q += __shfl_xor(q, 16, 64);
      s += __shfl_xor(s, 32, 64); q += __shfl_xor(q, 32, 64);
      if (lq == 0) {
        int gn = gnb + ni;
        atomicAdd(&bns[gn], s);
        atomicAdd(&bns[512 + gn], q);
      }
    }
  }
}

// ---------- CSR build ----------
__global__ void hist_k(const int* __restrict__ tgt, int* __restrict__ deg, int E) {
  for (int e = blockIdx.x * 256 + threadIdx.x; e < E; e += gridDim.x * 256)
    atomicAdd(&deg[tgt[e]], 1);
}

// multi-block scan: block sums -> 1-wave scan of partials -> per-block offsets.
__global__ void scan1_k(const int* __restrict__ deg, int* __restrict__ part, int n) {
  __shared__ int ws[16];
  int i = blockIdx.x * 1024 + threadIdx.x;
  int x = (i < n) ? deg[i] : 0;
#pragma unroll
  for (int off = 1; off < 64; off <<= 1) x += __shfl_xor(x, off, 64);
  if ((threadIdx.x & 63) == 0) ws[threadIdx.x >> 6] = x;
  __syncthreads();
  if (threadIdx.x == 0) {
    int s = 0;
#pragma unroll
    for (int j = 0; j < 16; j++) s += ws[j];
    part[blockIdx.x] = s;
  }
}

__global__ void scan2_k(const int* __restrict__ part, int* __restrict__ boff,
                        int* __restrict__ rowptr, int nb, int n) {
  int lane = threadIdx.x;
  int x = (lane < nb) ? part[lane] : 0;
  int v = x;
#pragma unroll
  for (int off = 1; off < 64; off <<= 1) {
    int t = __shfl_up(v, off, 64);
    if (lane >= off) v += t;
  }
  if (lane < nb) boff[lane] = v - x;  // exclusive
  if (lane == 63) rowptr[n] = v;      // grand total
}

__global__ void scan3_k(const int* __restrict__ deg, const int* __restrict__ boff,
                        int* __restrict__ rowptr, int* __restrict__ cursor, int n) {
  __shared__ int ws[16];
  const int lane = threadIdx.x & 63, wid = threadIdx.x >> 6;
  int i = blockIdx.x * 1024 + threadIdx.x;
  int x = (i < n) ? deg[i] : 0;
  int v = x;
#pragma unroll
  for (int off = 1; off < 64; off <<= 1) {
    int t = __shfl_up(v, off, 64);
    if (lane >= off) v += t;
  }
  if (lane == 63) ws[wid] = v;
  __syncthreads();
  if (wid == 0 && lane < 16) {
    int s = ws[lane];
#pragma unroll
    for (int off = 1; off < 16; off <<= 1) {
      int t = __shfl_up(s, off, 64);
      if (lane >= off) s += t;
    }
    ws[lane] = s;
  }
  __syncthreads();
  int pre = boff[blockIdx.x] + (wid ? ws[wid - 1] : 0) + (v - x);
  if (i < n) { rowptr[i] = pre; cursor[i] = pre; }
}

__global__ void scatter_k(const int* __restrict__ srci, const int* __restrict__ tgt,
                          int* __restrict__ cursor, int* __restrict__ esrc, int E) {
  for (int e = blockIdx.x * 256 + threadIdx.x; e < E; e += gridDim.x * 256) {
    int pos = atomicAdd(&cursor[tgt[e]], 1);
    esrc[pos] = srci[e];
  }
}

// ---------- attention: one WAVE per target node; lane covers 8 channels; 8 lanes/head ----
// v3: lane-resident index cache + 8-edge chunks, 16 K/V gathers in flight.
__global__ __launch_bounds__(256) void attn_k(
    const unsigned short* __restrict__ qkv, const int* __restrict__ rowptr,
    const int* __restrict__ esrc, unsigned short* __restrict__ aggb, int N)
{
  const int node = blockIdx.x * 4 + (threadIdx.x >> 6);
  const int lane = threadIdx.x & 63;
  if (node >= N) return;
  const int beg = rowptr[node], end = rowptr[node + 1];
  const uint4* qrow = (const uint4*)(qkv + (size_t)node * 1536);
  float qf[8];
  unpack8(qrow[lane], qf);
  float acc[8] = {0, 0, 0, 0, 0, 0, 0, 0};
  float ssum = 0.f;

  for (int blk = beg; blk < end; blk += 64) {
    const int nb = min(64, end - blk);
    int idxl = esrc[blk + (lane < nb ? lane : 0)];
    int i = 0;
    for (; i + 7 < nb; i += 8) {
      int e0 = __shfl(idxl, i + 0, 64), e1 = __shfl(idxl, i + 1, 64);
      int e2 = __shfl(idxl, i + 2, 64), e3 = __shfl(idxl, i + 3, 64);
      int e4 = __shfl(idxl, i + 4, 64), e5 = __shfl(idxl, i + 5, 64);
      int e6 = __shfl(idxl, i + 6, 64), e7 = __shfl(idxl, i + 7, 64);
      const uint4* b0 = (const uint4*)(qkv + (size_t)e0 * 1536);
      const uint4* b1 = (const uint4*)(qkv + (size_t)e1 * 1536);
      const uint4* b2 = (const uint4*)(qkv + (size_t)e2 * 1536);
      const uint4* b3 = (const uint4*)(qkv + (size_t)e3 * 1536);
      const uint4* b4 = (const uint4*)(qkv + (size_t)e4 * 1536);
      const uint4* b5 = (const uint4*)(qkv + (size_t)e5 * 1536);
      const uint4* b6 = (const uint4*)(qkv + (size_t)e6 * 1536);
      const uint4* b7 = (const uint4*)(qkv + (size_t)e7 * 1536);
      uint4 k0 = b0[64 + lane], k1 = b1[64 + lane], k2 = b2[64 + lane], k3 = b3[64 + lane];
      uint4 k4 = b4[64 + lane], k5 = b5[64 + lane], k6 = b6[64 + lane], k7 = b7[64 + lane];
      uint4 v0 = b0[128 + lane], v1 = b1[128 + lane], v2 = b2[128 + lane], v3 = b3[128 + lane];
      uint4 v4 = b4[128 + lane], v5 = b5[128 + lane], v6 = b6[128 + lane], v7 = b7[128 + lane];
      float kf[8];
      float p0 = 0.f, p1 = 0.f, p2 = 0.f, p3 = 0.f, p4 = 0.f, p5 = 0.f, p6 = 0.f, p7 = 0.f;
      unpack8(k0, kf);
#pragma unroll
      for (int j = 0; j < 8; j++) p0 += qf[j] * kf[j];
      unpack8(k1, kf);
#pragma unroll
      for (int j = 0; j < 8; j++) p1 += qf[j] * kf[j];
      unpack8(k2, kf);
#pragma unroll
      for (int j = 0; j < 8; j++) p2 += qf[j] * kf[j];
      unpack8(k3, kf);
#pragma unroll
      for (int j = 0; j < 8; j++) p3 += qf[j] * kf[j];
      unpack8(k4, kf);
#pragma unroll
      for (int j = 0; j < 8; j++) p4 += qf[j] * kf[j];
      unpack8(k5, kf);
#pragma unroll
      for (int j = 0; j < 8; j++) p5 += qf[j] * kf[j];
      unpack8(k6, kf);
#pragma unroll
      for (int j = 0; j < 8; j++) p6 += qf[j] * kf[j];
      unpack8(k7, kf);
#pragma unroll
      for (int j = 0; j < 8; j++) p7 += qf[j] * kf[j];
#pragma unroll
      for (int off = 1; off < 8; off <<= 1) {
        p0 += __shfl_xor(p0, off, 64); p1 += __shfl_xor(p1, off, 64);
        p2 += __shfl_xor(p2, off, 64); p3 += __shfl_xor(p3, off, 64);
        p4 += __shfl_xor(p4, off, 64); p5 += __shfl_xor(p5, off, 64);
        p6 += __shfl_xor(p6, off, 64); p7 += __shfl_xor(p7, off, 64);
      }
      float w0 = __expf(p0), w1 = __expf(p1), w2 = __expf(p2), w3 = __expf(p3);
      float w4 = __expf(p4), w5 = __expf(p5), w6 = __expf(p6), w7 = __expf(p7);
      ssum += ((w0 + w1) + (w2 + w3)) + ((w4 + w5) + (w6 + w7));
      float vf[8];
      unpack8(v0, vf);
#pragma unroll
      for (int j = 0; j < 8; j++) acc[j] += w0 * vf[j];
      unpack8(v1, vf);
#pragma unroll
      for (int j = 0; j < 8; j++) acc[j] += w1 * vf[j];
      unpack8(v2, vf);
#pragma unroll
      for (int j = 0; j < 8; j++) acc[j] += w2 * vf[j];
      unpack8(v3, vf);
#pragma unroll
      for (int j = 0; j < 8; j++) acc[j] += w3 * vf[j];
      unpack8(v4, vf);
#pragma unroll
      for (int j = 0; j < 8; j++) acc[j] += w4 * vf[j];
      unpack8(v5, vf);
#pragma unroll
      for (int j = 0; j < 8; j++) acc[j] += w5 * vf[j];
      unpack8(v6, vf);
#pragma unroll
      for (int j = 0; j < 8; j++) acc[j] += w6 * vf[j];
      unpack8(v7, vf);
#pragma unroll
      for (int j = 0; j < 8; j++) acc[j] += w7 * vf[j];
    }
    for (; i < nb; i++) {
      int e0 = __shfl(idxl, i, 64);
      const uint4* b0 = (const uint4*)(qkv + (size_t)e0 * 1536);
      uint4 k0 = b0[64 + lane], v0 = b0[128 + lane];
      float kf[8], vf[8];
      unpack8(k0, kf);
      float p0 = 0.f;
#pragma unroll
      for (int j = 0; j < 8; j++) p0 += qf[j] * kf[j];
#pragma unroll
      for (int off = 1; off < 8; off <<= 1) p0 += __shfl_xor(p0, off, 64);
      float w0 = __expf(p0);
      ssum += w0;
      unpack8(v0, vf);
#pragma unroll
      for (int j = 0; j < 8; j++) acc[j] += w0 * vf[j];
    }
  }
  float inv = 1.0f / (ssum + 1e-16f);
  uint4 o;
  o.x = pack2(acc[0] * inv, acc[1] * inv);
  o.y = pack2(acc[2] * inv, acc[3] * inv);
  o.z = pack2(acc[4] * inv, acc[5] * inv);
  o.w = pack2(acc[6] * inv, acc[7] * inv);
  ((uint4*)(aggb + (size_t)node * 512))[lane] = o;
}

// ---------- batchnorm apply (stats fused into GEMM epilogue); all-bf16 ----------
__global__ void bn_apply_k(const unsigned short* __restrict__ tb, const float* __restrict__ bns,
                           const float* __restrict__ g, const float* __restrict__ be,
                           unsigned short* __restrict__ xb, int N, int NPAD) {
  __shared__ float sa[512], sb[512];
  for (int c = threadIdx.x; c < 512; c += 256) {
    float mu = bns[c] / (float)N;
    float var = bns[512 + c] / (float)N - mu * mu;
    float inv = rsqrtf(var + 1e-5f);
    float ga = g[c] * inv;
    sa[c] = ga;
    sb[c] = be[c] - mu * ga;
  }
  __syncthreads();
  size_t total = (size_t)NPAD * 512;
  for (size_t idx = (size_t)blockIdx.x * 256 + threadIdx.x; idx < total; idx += (size_t)gridDim.x * 256) {
    int r = (int)(idx >> 9);
    int c = (int)(idx & 511);
    float v = 0.f;
    if (r < N) v = b2f(tb[idx]) * sa[c] + sb[c];
    xb[idx] = f2b(v);
  }
}

// ---------- fused final BN + LayerNorm ----------
__global__ __launch_bounds__(256) void bn_ln_k(
    const unsigned short* __restrict__ tb, const float* __restrict__ bns,
    const float* __restrict__ g, const float* __restrict__ be,
    const float* __restrict__ lng, const float* __restrict__ lnb,
    float* __restrict__ out, int N)
{
  int row = blockIdx.x * 4 + (threadIdx.x >> 6);
  int lane = threadIdx.x & 63;
  if (row >= N) return;
  const int c0 = lane * 8;
  const float invN = 1.0f / (float)N;
  float sa[8], sb[8];
#pragma unroll
  for (int j = 0; j < 8; j++) {
    float mu = bns[c0 + j] * invN;
    float var = bns[512 + c0 + j] * invN - mu * mu;
    float ga = g[c0 + j] * rsqrtf(var + 1e-5f);
    sa[j] = ga;
    sb[j] = be[c0 + j] - mu * ga;
  }
  const uint4* xr = (const uint4*)(tb + (size_t)row * 512);
  float v[8];
  unpack8(xr[lane], v);
#pragma unroll
  for (int j = 0; j < 8; j++) v[j] = v[j] * sa[j] + sb[j];
  float s = 0.f, q = 0.f;
#pragma unroll
  for (int j = 0; j < 8; j++) { s += v[j]; q += v[j] * v[j]; }
#pragma unroll
  for (int off = 32; off > 0; off >>= 1) { s += __shfl_xor(s, off, 64); q += __shfl_xor(q, off, 64); }
  float mu = s * (1.0f / 512.0f);
  float var = q * (1.0f / 512.0f) - mu * mu;
  float inv = rsqrtf(var + 1e-5f);
  float* orow = out + (size_t)row * 512;
#pragma unroll
  for (int j = 0; j < 8; j++)
    orow[c0 + j] = (v[j] - mu) * inv * lng[c0 + j] + lnb[c0 + j];
}

// ---------- conversions (float4-vectorized, G13) ----------
__global__ void cvt3_k(const float4* __restrict__ a, uint2* __restrict__ oa, size_t na4,
                       const float4* __restrict__ b, uint2* __restrict__ ob, size_t nb4,
                       const float4* __restrict__ c, uint2* __restrict__ oc, size_t nc4) {
  size_t stride = (size_t)gridDim.x * 256;
  size_t t0 = (size_t)blockIdx.x * 256 + threadIdx.x;
  for (size_t i = t0; i < na4; i += stride) {
    float4 v = a[i];
    oa[i] = (uint2){pack2(v.x, v.y), pack2(v.z, v.w)};
  }
  for (size_t i = t0; i < nb4; i += stride) {
    float4 v = b[i];
    ob[i] = (uint2){pack2(v.x, v.y), pack2(v.z, v.w)};
  }
  for (size_t i = t0; i < nc4; i += stride) {
    float4 v = c[i];
    oc[i] = (uint2){pack2(v.x, v.y), pack2(v.z, v.w)};
  }
}

// wqkv: [2][1536][512] bf16 (q rows prescaled by 0.125); bqkv: [2][1536] fp32
__global__ void build_qkvw_k(const float4* __restrict__ Wq4, const float4* __restrict__ Wk4,
                             const float4* __restrict__ Wv4, const float* __restrict__ bq,
                             uint2* __restrict__ wqkv4, float* __restrict__ bqkv) {
  const size_t total4 = (size_t)2 * 1536 * 128;  // 128 float4 per 512-col row
  for (size_t idx = (size_t)blockIdx.x * 256 + threadIdx.x; idx < total4; idx += (size_t)gridDim.x * 256) {
    int l = (int)(idx / (1536 * 128));
    int rem = (int)(idx % (1536 * 128));
    int rr = rem >> 7, c4 = rem & 127;
    float4 v;
    if (rr < 512) {
      v = Wq4[(size_t)l * 65536 + rr * 128 + c4];
      v.x *= 0.125f; v.y *= 0.125f; v.z *= 0.125f; v.w *= 0.125f;
    } else if (rr < 1024) {
      v = Wk4[(size_t)l * 65536 + (rr - 512) * 128 + c4];
    } else {
      v = Wv4[(size_t)l * 65536 + (rr - 1024) * 128 + c4];
    }
    wqkv4[idx] = (uint2){pack2(v.x, v.y), pack2(v.z, v.w)};
  }
  for (int i = blockIdx.x * 256 + threadIdx.x; i < 2 * 1536; i += gridDim.x * 256) {
    int l = i / 1536, rr = i % 1536;
    bqkv[i] = (rr < 512) ? bq[l * 512 + rr] * 0.125f : 0.f;
  }
}

__global__ void src_pad_k(const float4* __restrict__ src4, uint2* __restrict__ xb4,
                          int N, int NPAD) {
  size_t total4 = (size_t)NPAD * 128;
  size_t nvalid = (size_t)N * 128;
  for (size_t i = (size_t)blockIdx.x * 256 + threadIdx.x; i < total4; i += (size_t)gridDim.x * 256) {
    uint2 o = {0u, 0u};
    if (i < nvalid) {
      float4 v = src4[i];
      o = (uint2){pack2(v.x, v.y), pack2(v.z, v.w)};
    }
    xb4[i] = o;
  }
}

// ---------- launch ----------
extern "C" void kernel_launch(void* const* d_in, const int* in_sizes, int n_in,
                              void* d_out, int out_size, void* d_ws, size_t ws_size,
                              hipStream_t stream)
{
  const float* src = (const float*)d_in[0];
  const int* eidx = (const int*)d_in[1];
  const float* Wq = (const float*)d_in[2];
  const float* bq = (const float*)d_in[3];
  const float* Wk = (const float*)d_in[4];
  const float* Wv = (const float*)d_in[5];
  const float* Wo = (const float*)d_in[6];
  const float* bo = (const float*)d_in[7];
  const float* W1 = (const float*)d_in[8];
  const float* b1 = (const float*)d_in[9];
  const float* W2 = (const float*)d_in[10];
  const float* b2 = (const float*)d_in[11];
  const float* g1 = (const float*)d_in[12];
  const float* be1 = (const float*)d_in[13];
  const float* g2 = (const float*)d_in[14];
  const float* be2 = (const float*)d_in[15];
  const float* lng = (const float*)d_in[16];
  const float* lnb = (const float*)d_in[17];

  const int N = in_sizes[0] / 512;
  const int E = in_sizes[1] / 2;
  const int NPAD = ((N + 1023) / 1024) * 1024;  // m-tiles divisible by 8 (XCD swizzle)
  const int MT = NPAD / 128;
  const int XCHUNK = MT / 8;
  const int NB = (N + 1023) / 1024;             // scan blocks (<= 64)

  char* w = (char*)d_ws;
  size_t off = 0;
  auto alloc = [&](size_t b) -> char* { char* p = w + off; off = (off + b + 255) & ~(size_t)255; return p; };
  unsigned short* qkvb = (unsigned short*)alloc((size_t)NPAD * 1536 * 2);
  unsigned short* aggb = (unsigned short*)alloc((size_t)NPAD * 512 * 2);
  unsigned short* hb   = qkvb;  // FF hidden; qkv/agg dead by then
  unsigned short* xb   = (unsigned short*)alloc((size_t)NPAD * 512 * 2);
  unsigned short* tb   = (unsigned short*)alloc((size_t)NPAD * 512 * 2);  // pre-BN tmp
  unsigned short* wqkv = (unsigned short*)alloc((size_t)2 * 1536 * 512 * 2);
  float* bqkv          = (float*)alloc((size_t)2 * 1536 * 4);
  unsigned short* wWo = (unsigned short*)alloc((size_t)2 * 512 * 512 * 2);
  unsigned short* wW1 = (unsigned short*)alloc((size_t)2 * 2048 * 512 * 2);
  unsigned short* wW2 = (unsigned short*)alloc((size_t)2 * 512 * 2048 * 2);
  int* rowptr = (int*)alloc((size_t)(N + 1) * 4);
  int* cursor = (int*)alloc((size_t)N * 4);
  int* deg    = (int*)alloc((size_t)N * 4);
  int* esrc   = (int*)alloc((size_t)E * 4);
  float* bnsum = (float*)alloc(4096 * 4);
  int* bpart  = (int*)alloc(64 * 4);
  int* boff2  = (int*)alloc(64 * 4);
  (void)ws_size; (void)n_in; (void)out_size;

  const int* srci = eidx;
  const int* tgt  = eidx + E;

  hipMemsetAsync(deg, 0, (size_t)N * 4, stream);
  hipMemsetAsync(bnsum, 0, 4096 * 4, stream);

  src_pad_k<<<2048, 256, 0, stream>>>((const float4*)src, (uint2*)xb, N, NPAD);
  build_qkvw_k<<<1024, 256, 0, stream>>>((const float4*)Wq, (const float4*)Wk,
                                         (const float4*)Wv, bq, (uint2*)wqkv, bqkv);
  cvt3_k<<<1024, 256, 0, stream>>>(
      (const float4*)Wo, (uint2*)wWo, (size_t)2 * 512 * 512 / 4,
      (const float4*)W1, (uint2*)wW1, (size_t)2 * 2048 * 512 / 4,
      (const float4*)W2, (uint2*)wW2, (size_t)2 * 512 * 2048 / 4);
  hist_k<<<1250, 256, 0, stream>>>(tgt, deg, E);
  scan1_k<<<NB, 1024, 0, stream>>>(deg, bpart, N);
  scan2_k<<<1, 64, 0, stream>>>(bpart, boff2, rowptr, NB, N);
  scan3_k<<<NB, 1024, 0, stream>>>(deg, boff2, rowptr, cursor, N);
  scatter_k<<<1250, 256, 0, stream>>>(srci, tgt, cursor, esrc, E);

  for (int l = 0; l < 2; l++) {
    const unsigned short* Wqkv_l = wqkv + (size_t)l * 1536 * 512;
    const unsigned short* Wo_l = wWo + (size_t)l * 512 * 512;
    const unsigned short* W1_l = wW1 + (size_t)l * 2048 * 512;
    const unsigned short* W2_l = wW2 + (size_t)l * 512 * 2048;
    float* bns1 = bnsum + (size_t)(l * 2 + 0) * 1024;
    float* bns2 = bnsum + (size_t)(l * 2 + 1) * 1024;

    // QKV: Nn=1536, YT=12
    gemm_bt<<<MT * 12, 256, 0, stream>>>(
        xb, Wqkv_l, bqkv + l * 1536, 0, nullptr, qkvb, nullptr, 0, 1536, 512, 12, XCHUNK);
    attn_k<<<(N + 3) / 4, 256, 0, stream>>>(qkvb, rowptr, esrc, aggb, N);
    // Wo: resid=xb (layer input), out tb + fused BN stats; YT=4
    gemm_bt<<<MT * 4, 256, 0, stream>>>(
        aggb, Wo_l, bo + l * 512, 0, xb, tb, bns1, N, 512, 512, 4, XCHUNK);
    bn_apply_k<<<2048, 256, 0, stream>>>(tb, bns1, g1 + l * 512, be1 + l * 512, xb, N, NPAD);
    // FF1: Nn=2048, YT=16
    gemm_bt<<<MT * 16, 256, 0, stream>>>(
        xb, W1_l, b1 + l * 2048, 1, nullptr, hb, nullptr, 0, 2048, 512, 16, XCHUNK);
    // FF2: K=2048, resid=xb (post-BN1), out tb + fused BN stats; YT=4
    gemm_bt<<<MT * 4, 256, 0, stream>>>(
        hb, W2_l, b2 + l * 512, 0, xb, tb, bns2, N, 512, 2048, 4, XCHUNK);
    if (l == 0) {
      bn_apply_k<<<2048, 256, 0, stream>>>(tb, bns2, g2 + l * 512, be2 + l * 512, xb, N, NPAD);
    } else {
      bn_ln_k<<<(N + 3) / 4, 256, 0, stream>>>(
          tb, bns2, g2 + l * 512, be2 + l * 512, lng, lnb, (float*)d_out, N);
    }
  }
}

// Round 10
// 827.101 us; speedup vs baseline: 1.1057x; 1.1057x over previous
//
#include <hip/hip_runtime.h>
#include <stdint.h>

typedef __attribute__((ext_vector_type(4))) float f32x4;
typedef __attribute__((ext_vector_type(8))) short bf16x8;

__device__ __forceinline__ float bitsf(unsigned u) {
  union { unsigned u; float f; } x; x.u = u; return x.f;
}
__device__ __forceinline__ float b2f(unsigned short u) { return bitsf(((unsigned)u) << 16); }
__device__ __forceinline__ unsigned short f2b(float f) {
  union { float f; unsigned u; } x; x.f = f;
  unsigned r = x.u + 0x7FFFu + ((x.u >> 16) & 1u);
  return (unsigned short)(r >> 16);
}
__device__ __forceinline__ unsigned pack2(float lo, float hi) {
  return ((unsigned)f2b(hi) << 16) | f2b(lo);
}
__device__ __forceinline__ void async16(const void* g, void* l) {
  __builtin_amdgcn_global_load_lds((const __attribute__((address_space(1))) unsigned*)g,
                                   (__attribute__((address_space(3))) unsigned*)l, 16, 0, 0);
}
__device__ __forceinline__ void unpack8(uint4 u, float* f) {
  f[0] = bitsf(u.x << 16); f[1] = bitsf(u.x & 0xFFFF0000u);
  f[2] = bitsf(u.y << 16); f[3] = bitsf(u.y & 0xFFFF0000u);
  f[4] = bitsf(u.z << 16); f[5] = bitsf(u.z & 0xFFFF0000u);
  f[6] = bitsf(u.w << 16); f[7] = bitsf(u.w & 0xFFFF0000u);
}

// out[m,n] = relu?(acc+bias) (+resid); A: MxK bf16 rm, B: NnxK bf16 rm.
// ROUND-8 PROVEN STRUCTURE (851us total), reverted byte-identical: BK=64
// (32KB LDS), 2-barrier per K-step, 8 async16/thread per K-step. Three
// structure-rewrite attempts (dbuf r4, small-tile r7, counted-vmcnt r9) all
// regressed -- this is the structure's measured optimum at these shapes.
// New optional raff: per-column affine on the residual load
// (v += resid*raff[n] + raff[512+n]) -- used for folded-BN residual paths.
// XCD swizzle: b -> xcd=b&7, slot=b>>3; y = slot % YT, x = xcd*XCHUNK + slot/YT.
// A LDS swizzle: sigmaA(r)=r&7. B: sigmaB(r)=(r>>2)&7 so fragment ni, lane lr
// reads row lr*4+ni -> lane's 4 ni cols consecutive => packed uint2 epilogue.
__global__ __launch_bounds__(256, 3) void gemm_bt(
    const unsigned short* __restrict__ A, const unsigned short* __restrict__ B,
    const float* __restrict__ bias, int relu,
    const unsigned short* __restrict__ residb,
    const float* __restrict__ raff,
    unsigned short* __restrict__ outb,
    float* __restrict__ bns, int statN,
    int Nn, int K, int YT, int XCHUNK)
{
  __shared__ __attribute__((aligned(16))) unsigned short As[128 * 64];
  __shared__ __attribute__((aligned(16))) unsigned short Bs[128 * 64];
  const int b = blockIdx.x;
  const int slot = b >> 3;
  const int m0 = ((b & 7) * XCHUNK + slot / YT) * 128;
  const int n0 = (slot % YT) * 128;
  const int tid = threadIdx.x;
  const int lane = tid & 63;
  const int wave = tid >> 6;
  const int wm = (wave & 1) * 64, wn = (wave >> 1) * 64;
  const int lr = lane & 15, lq = lane >> 4;

  f32x4 acc[4][4];
#pragma unroll
  for (int i = 0; i < 4; i++)
#pragma unroll
    for (int j = 0; j < 4; j++) acc[i][j] = (f32x4){0.f, 0.f, 0.f, 0.f};

  const int rloc = lane >> 3;
  const int rq = rloc >> 2;
  const int gswA = (lane & 7) ^ rloc;
  const int rA = 32 * wave + rloc;
  const unsigned short* gA = A + (size_t)(m0 + rA) * K + gswA * 8;
  const unsigned short* gB0 = B + (size_t)(n0 + rA) * K +      (((lane & 7) ^ ((0 + rq) & 7)) * 8);
  const unsigned short* gB1 = B + (size_t)(n0 + rA + 8) * K +  (((lane & 7) ^ ((2 + rq) & 7)) * 8);
  const unsigned short* gB2 = B + (size_t)(n0 + rA + 16) * K + (((lane & 7) ^ ((4 + rq) & 7)) * 8);
  const unsigned short* gB3 = B + (size_t)(n0 + rA + 24) * K + (((lane & 7) ^ ((6 + rq) & 7)) * 8);
  char* lA = (char*)As + wave * 4096;
  char* lB = (char*)Bs + wave * 4096;
  const int sxa = lr & 7;

  for (int k0 = 0; k0 < K; k0 += 64) {
    async16(gA + k0,          lA);
    async16(gA + 8 * K + k0,  lA + 1024);
    async16(gA + 16 * K + k0, lA + 2048);
    async16(gA + 24 * K + k0, lA + 3072);
    async16(gB0 + k0, lB);
    async16(gB1 + k0, lB + 1024);
    async16(gB2 + k0, lB + 2048);
    async16(gB3 + k0, lB + 3072);
    __syncthreads();

    for (int ks = 0; ks < 2; ks++) {
      const int spos = (((ks << 2) + lq) ^ sxa) << 3;
      bf16x8 af[4], bfr[4];
#pragma unroll
      for (int mi = 0; mi < 4; mi++)
        af[mi] = *(const bf16x8*)&As[(wm + mi * 16 + lr) * 64 + spos];
#pragma unroll
      for (int ni = 0; ni < 4; ni++)
        bfr[ni] = *(const bf16x8*)&Bs[(wn + lr * 4 + ni) * 64 + spos];
#pragma unroll
      for (int mi = 0; mi < 4; mi++)
#pragma unroll
        for (int ni = 0; ni < 4; ni++)
          acc[mi][ni] = __builtin_amdgcn_mfma_f32_16x16x32_bf16(af[mi], bfr[ni], acc[mi][ni], 0, 0, 0);
    }
    __syncthreads();
  }

  float sn[4] = {0, 0, 0, 0}, qn[4] = {0, 0, 0, 0};
  const int gnb = n0 + wn + lr * 4;
  float4 bv = {0.f, 0.f, 0.f, 0.f};
  if (bias) bv = *(const float4*)&bias[gnb];
  float4 ra = {1.f, 1.f, 1.f, 1.f}, rb4 = {0.f, 0.f, 0.f, 0.f};
  if (raff) {
    ra = *(const float4*)&raff[gnb];
    rb4 = *(const float4*)&raff[512 + gnb];
  }
#pragma unroll
  for (int mi = 0; mi < 4; mi++) {
#pragma unroll
    for (int r = 0; r < 4; r++) {
      int gm = m0 + wm + mi * 16 + lq * 4 + r;
      size_t base = (size_t)gm * Nn + gnb;
      float v0 = acc[mi][0][r] + bv.x;
      float v1 = acc[mi][1][r] + bv.y;
      float v2 = acc[mi][2][r] + bv.z;
      float v3 = acc[mi][3][r] + bv.w;
      if (relu) {
        v0 = fmaxf(v0, 0.f); v1 = fmaxf(v1, 0.f);
        v2 = fmaxf(v2, 0.f); v3 = fmaxf(v3, 0.f);
      }
      if (residb) {
        uint2 rb = *(const uint2*)&residb[base];
        if (raff) {
          v0 += bitsf(rb.x << 16) * ra.x + rb4.x;
          v1 += bitsf(rb.x & 0xFFFF0000u) * ra.y + rb4.y;
          v2 += bitsf(rb.y << 16) * ra.z + rb4.z;
          v3 += bitsf(rb.y & 0xFFFF0000u) * ra.w + rb4.w;
        } else {
          v0 += bitsf(rb.x << 16); v1 += bitsf(rb.x & 0xFFFF0000u);
          v2 += bitsf(rb.y << 16); v3 += bitsf(rb.y & 0xFFFF0000u);
        }
      }
      uint2 o;
      o.x = pack2(v0, v1);
      o.y = pack2(v2, v3);
      *(uint2*)&outb[base] = o;
      if (bns && gm < statN) {
        sn[0] += v0; qn[0] += v0 * v0;
        sn[1] += v1; qn[1] += v1 * v1;
        sn[2] += v2; qn[2] += v2 * v2;
        sn[3] += v3; qn[3] += v3 * v3;
      }
    }
  }
  if (bns) {
#pragma unroll
    for (int ni = 0; ni < 4; ni++) {
      float s = sn[ni], q = qn[ni];
      s += __shfl_xor(s, 16, 64); q += __shfl_xor(q, 16, 64);
      s += __shfl_xor(s, 32, 64); q += __shfl_xor(q, 32, 64);
      if (lq == 0) {
        int gn = gnb + ni;
        atomicAdd(&bns[gn], s);
        atomicAdd(&bns[512 + gn], q);
      }
    }
  }
}

// ---------- BN weight-fold: wdst[f][c] = wsrc[f][c]*sa[c];
// bdst[f] = bsrc[f] + sum_c wsrc[f][c]*sb[c]; co = {sa[512], sb[512]}.
// sa/sb derived from bns stats: BN(t)@W^T = t@(W*sa)^T + (b + W.sb).
// Each wave handles one f row (lane covers 8 cols). Block 0 also writes co.
__global__ __launch_bounds__(256) void wtrans_k(
    const unsigned short* __restrict__ wsrc, const float* __restrict__ bsrc,
    const float* __restrict__ bns, const float* __restrict__ g,
    const float* __restrict__ be, int N, int F,
    unsigned short* __restrict__ wdst, float* __restrict__ bdst,
    float* __restrict__ co)
{
  __shared__ float ssa[512], ssb[512];
  const float invN = 1.0f / (float)N;
  for (int c = threadIdx.x; c < 512; c += 256) {
    float mu = bns[c] * invN;
    float var = bns[512 + c] * invN - mu * mu;
    float ga = g[c] * rsqrtf(var + 1e-5f);
    ssa[c] = ga;
    ssb[c] = be[c] - mu * ga;
  }
  __syncthreads();
  if (blockIdx.x == 0) {
    for (int c = threadIdx.x; c < 512; c += 256) {
      co[c] = ssa[c];
      co[512 + c] = ssb[c];
    }
  }
  const int lane = threadIdx.x & 63, wv = threadIdx.x >> 6;
  const int c0 = lane * 8;
  for (int f = blockIdx.x * 4 + wv; f < F; f += gridDim.x * 4) {
    bf16x8 wrow = *(const bf16x8*)&wsrc[(size_t)f * 512 + c0];
    float d = 0.f;
    uint4 o;
    float w0 = b2f((unsigned short)wrow[0]), w1 = b2f((unsigned short)wrow[1]);
    float w2 = b2f((unsigned short)wrow[2]), w3 = b2f((unsigned short)wrow[3]);
    float w4 = b2f((unsigned short)wrow[4]), w5 = b2f((unsigned short)wrow[5]);
    float w6 = b2f((unsigned short)wrow[6]), w7 = b2f((unsigned short)wrow[7]);
    d = w0 * ssb[c0] + w1 * ssb[c0 + 1] + w2 * ssb[c0 + 2] + w3 * ssb[c0 + 3]
      + w4 * ssb[c0 + 4] + w5 * ssb[c0 + 5] + w6 * ssb[c0 + 6] + w7 * ssb[c0 + 7];
    o.x = pack2(w0 * ssa[c0],     w1 * ssa[c0 + 1]);
    o.y = pack2(w2 * ssa[c0 + 2], w3 * ssa[c0 + 3]);
    o.z = pack2(w4 * ssa[c0 + 4], w5 * ssa[c0 + 5]);
    o.w = pack2(w6 * ssa[c0 + 6], w7 * ssa[c0 + 7]);
    *(uint4*)&wdst[(size_t)f * 512 + c0] = o;
#pragma unroll
    for (int off = 1; off < 64; off <<= 1) d += __shfl_xor(d, off, 64);
    if (lane == 0) bdst[f] = bsrc[f] + d;
  }
}

// ---------- CSR build ----------
__global__ void hist_k(const int* __restrict__ tgt, int* __restrict__ deg, int E) {
  for (int e = blockIdx.x * 256 + threadIdx.x; e < E; e += gridDim.x * 256)
    atomicAdd(&deg[tgt[e]], 1);
}

// multi-block scan: block sums -> 1-wave scan of partials -> per-block offsets.
__global__ void scan1_k(const int* __restrict__ deg, int* __restrict__ part, int n) {
  __shared__ int ws[16];
  int i = blockIdx.x * 1024 + threadIdx.x;
  int x = (i < n) ? deg[i] : 0;
#pragma unroll
  for (int off = 1; off < 64; off <<= 1) x += __shfl_xor(x, off, 64);
  if ((threadIdx.x & 63) == 0) ws[threadIdx.x >> 6] = x;
  __syncthreads();
  if (threadIdx.x == 0) {
    int s = 0;
#pragma unroll
    for (int j = 0; j < 16; j++) s += ws[j];
    part[blockIdx.x] = s;
  }
}

__global__ void scan2_k(const int* __restrict__ part, int* __restrict__ boff,
                        int* __restrict__ rowptr, int nb, int n) {
  int lane = threadIdx.x;
  int x = (lane < nb) ? part[lane] : 0;
  int v = x;
#pragma unroll
  for (int off = 1; off < 64; off <<= 1) {
    int t = __shfl_up(v, off, 64);
    if (lane >= off) v += t;
  }
  if (lane < nb) boff[lane] = v - x;  // exclusive
  if (lane == 63) rowptr[n] = v;      // grand total
}

__global__ void scan3_k(const int* __restrict__ deg, const int* __restrict__ boff,
                        int* __restrict__ rowptr, int* __restrict__ cursor, int n) {
  __shared__ int ws[16];
  const int lane = threadIdx.x & 63, wid = threadIdx.x >> 6;
  int i = blockIdx.x * 1024 + threadIdx.x;
  int x = (i < n) ? deg[i] : 0;
  int v = x;
#pragma unroll
  for (int off = 1; off < 64; off <<= 1) {
    int t = __shfl_up(v, off, 64);
    if (lane >= off) v += t;
  }
  if (lane == 63) ws[wid] = v;
  __syncthreads();
  if (wid == 0 && lane < 16) {
    int s = ws[lane];
#pragma unroll
    for (int off = 1; off < 16; off <<= 1) {
      int t = __shfl_up(s, off, 64);
      if (lane >= off) s += t;
    }
    ws[lane] = s;
  }
  __syncthreads();
  int pre = boff[blockIdx.x] + (wid ? ws[wid - 1] : 0) + (v - x);
  if (i < n) { rowptr[i] = pre; cursor[i] = pre; }
}

__global__ void scatter_k(const int* __restrict__ srci, const int* __restrict__ tgt,
                          int* __restrict__ cursor, int* __restrict__ esrc, int E) {
  for (int e = blockIdx.x * 256 + threadIdx.x; e < E; e += gridDim.x * 256) {
    int pos = atomicAdd(&cursor[tgt[e]], 1);
    esrc[pos] = srci[e];
  }
}

// ---------- attention: one WAVE per target node; lane covers 8 channels; 8 lanes/head ----
// v3: lane-resident index cache + 8-edge chunks, 16 K/V gathers in flight.
__global__ __launch_bounds__(256) void attn_k(
    const unsigned short* __restrict__ qkv, const int* __restrict__ rowptr,
    const int* __restrict__ esrc, unsigned short* __restrict__ aggb, int N)
{
  const int node = blockIdx.x * 4 + (threadIdx.x >> 6);
  const int lane = threadIdx.x & 63;
  if (node >= N) return;
  const int beg = rowptr[node], end = rowptr[node + 1];
  const uint4* qrow = (const uint4*)(qkv + (size_t)node * 1536);
  float qf[8];
  unpack8(qrow[lane], qf);
  float acc[8] = {0, 0, 0, 0, 0, 0, 0, 0};
  float ssum = 0.f;

  for (int blk = beg; blk < end; blk += 64) {
    const int nb = min(64, end - blk);
    int idxl = esrc[blk + (lane < nb ? lane : 0)];
    int i = 0;
    for (; i + 7 < nb; i += 8) {
      int e0 = __shfl(idxl, i + 0, 64), e1 = __shfl(idxl, i + 1, 64);
      int e2 = __shfl(idxl, i + 2, 64), e3 = __shfl(idxl, i + 3, 64);
      int e4 = __shfl(idxl, i + 4, 64), e5 = __shfl(idxl, i + 5, 64);
      int e6 = __shfl(idxl, i + 6, 64), e7 = __shfl(idxl, i + 7, 64);
      const uint4* b0 = (const uint4*)(qkv + (size_t)e0 * 1536);
      const uint4* b1 = (const uint4*)(qkv + (size_t)e1 * 1536);
      const uint4* b2 = (const uint4*)(qkv + (size_t)e2 * 1536);
      const uint4* b3 = (const uint4*)(qkv + (size_t)e3 * 1536);
      const uint4* b4 = (const uint4*)(qkv + (size_t)e4 * 1536);
      const uint4* b5 = (const uint4*)(qkv + (size_t)e5 * 1536);
      const uint4* b6 = (const uint4*)(qkv + (size_t)e6 * 1536);
      const uint4* b7 = (const uint4*)(qkv + (size_t)e7 * 1536);
      uint4 k0 = b0[64 + lane], k1 = b1[64 + lane], k2 = b2[64 + lane], k3 = b3[64 + lane];
      uint4 k4 = b4[64 + lane], k5 = b5[64 + lane], k6 = b6[64 + lane], k7 = b7[64 + lane];
      uint4 v0 = b0[128 + lane], v1 = b1[128 + lane], v2 = b2[128 + lane], v3 = b3[128 + lane];
      uint4 v4 = b4[128 + lane], v5 = b5[128 + lane], v6 = b6[128 + lane], v7 = b7[128 + lane];
      float kf[8];
      float p0 = 0.f, p1 = 0.f, p2 = 0.f, p3 = 0.f, p4 = 0.f, p5 = 0.f, p6 = 0.f, p7 = 0.f;
      unpack8(k0, kf);
#pragma unroll
      for (int j = 0; j < 8; j++) p0 += qf[j] * kf[j];
      unpack8(k1, kf);
#pragma unroll
      for (int j = 0; j < 8; j++) p1 += qf[j] * kf[j];
      unpack8(k2, kf);
#pragma unroll
      for (int j = 0; j < 8; j++) p2 += qf[j] * kf[j];
      unpack8(k3, kf);
#pragma unroll
      for (int j = 0; j < 8; j++) p3 += qf[j] * kf[j];
      unpack8(k4, kf);
#pragma unroll
      for (int j = 0; j < 8; j++) p4 += qf[j] * kf[j];
      unpack8(k5, kf);
#pragma unroll
      for (int j = 0; j < 8; j++) p5 += qf[j] * kf[j];
      unpack8(k6, kf);
#pragma unroll
      for (int j = 0; j < 8; j++) p6 += qf[j] * kf[j];
      unpack8(k7, kf);
#pragma unroll
      for (int j = 0; j < 8; j++) p7 += qf[j] * kf[j];
#pragma unroll
      for (int off = 1; off < 8; off <<= 1) {
        p0 += __shfl_xor(p0, off, 64); p1 += __shfl_xor(p1, off, 64);
        p2 += __shfl_xor(p2, off, 64); p3 += __shfl_xor(p3, off, 64);
        p4 += __shfl_xor(p4, off, 64); p5 += __shfl_xor(p5, off, 64);
        p6 += __shfl_xor(p6, off, 64); p7 += __shfl_xor(p7, off, 64);
      }
      float w0 = __expf(p0), w1 = __expf(p1), w2 = __expf(p2), w3 = __expf(p3);
      float w4 = __expf(p4), w5 = __expf(p5), w6 = __expf(p6), w7 = __expf(p7);
      ssum += ((w0 + w1) + (w2 + w3)) + ((w4 + w5) + (w6 + w7));
      float vf[8];
      unpack8(v0, vf);
#pragma unroll
      for (int j = 0; j < 8; j++) acc[j] += w0 * vf[j];
      unpack8(v1, vf);
#pragma unroll
      for (int j = 0; j < 8; j++) acc[j] += w1 * vf[j];
      unpack8(v2, vf);
#pragma unroll
      for (int j = 0; j < 8; j++) acc[j] += w2 * vf[j];
      unpack8(v3, vf);
#pragma unroll
      for (int j = 0; j < 8; j++) acc[j] += w3 * vf[j];
      unpack8(v4, vf);
#pragma unroll
      for (int j = 0; j < 8; j++) acc[j] += w4 * vf[j];
      unpack8(v5, vf);
#pragma unroll
      for (int j = 0; j < 8; j++) acc[j] += w5 * vf[j];
      unpack8(v6, vf);
#pragma unroll
      for (int j = 0; j < 8; j++) acc[j] += w6 * vf[j];
      unpack8(v7, vf);
#pragma unroll
      for (int j = 0; j < 8; j++) acc[j] += w7 * vf[j];
    }
    for (; i < nb; i++) {
      int e0 = __shfl(idxl, i, 64);
      const uint4* b0 = (const uint4*)(qkv + (size_t)e0 * 1536);
      uint4 k0 = b0[64 + lane], v0 = b0[128 + lane];
      float kf[8], vf[8];
      unpack8(k0, kf);
      float p0 = 0.f;
#pragma unroll
      for (int j = 0; j < 8; j++) p0 += qf[j] * kf[j];
#pragma unroll
      for (int off = 1; off < 8; off <<= 1) p0 += __shfl_xor(p0, off, 64);
      float w0 = __expf(p0);
      ssum += w0;
      unpack8(v0, vf);
#pragma unroll
      for (int j = 0; j < 8; j++) acc[j] += w0 * vf[j];
    }
  }
  float inv = 1.0f / (ssum + 1e-16f);
  uint4 o;
  o.x = pack2(acc[0] * inv, acc[1] * inv);
  o.y = pack2(acc[2] * inv, acc[3] * inv);
  o.z = pack2(acc[4] * inv, acc[5] * inv);
  o.w = pack2(acc[6] * inv, acc[7] * inv);
  ((uint4*)(aggb + (size_t)node * 512))[lane] = o;
}

// ---------- fused final BN + LayerNorm ----------
__global__ __launch_bounds__(256) void bn_ln_k(
    const unsigned short* __restrict__ tb, const float* __restrict__ bns,
    const float* __restrict__ g, const float* __restrict__ be,
    const float* __restrict__ lng, const float* __restrict__ lnb,
    float* __restrict__ out, int N)
{
  int row = blockIdx.x * 4 + (threadIdx.x >> 6);
  int lane = threadIdx.x & 63;
  if (row >= N) return;
  const int c0 = lane * 8;
  const float invN = 1.0f / (float)N;
  float sa[8], sb[8];
#pragma unroll
  for (int j = 0; j < 8; j++) {
    float mu = bns[c0 + j] * invN;
    float var = bns[512 + c0 + j] * invN - mu * mu;
    float ga = g[c0 + j] * rsqrtf(var + 1e-5f);
    sa[j] = ga;
    sb[j] = be[c0 + j] - mu * ga;
  }
  const uint4* xr = (const uint4*)(tb + (size_t)row * 512);
  float v[8];
  unpack8(xr[lane], v);
#pragma unroll
  for (int j = 0; j < 8; j++) v[j] = v[j] * sa[j] + sb[j];
  float s = 0.f, q = 0.f;
#pragma unroll
  for (int j = 0; j < 8; j++) { s += v[j]; q += v[j] * v[j]; }
#pragma unroll
  for (int off = 32; off > 0; off >>= 1) { s += __shfl_xor(s, off, 64); q += __shfl_xor(q, off, 64); }
  float mu = s * (1.0f / 512.0f);
  float var = q * (1.0f / 512.0f) - mu * mu;
  float inv = rsqrtf(var + 1e-5f);
  float* orow = out + (size_t)row * 512;
#pragma unroll
  for (int j = 0; j < 8; j++)
    orow[c0 + j] = (v[j] - mu) * inv * lng[c0 + j] + lnb[c0 + j];
}

// ---------- conversions (float4-vectorized, G13) ----------
__global__ void cvt3_k(const float4* __restrict__ a, uint2* __restrict__ oa, size_t na4,
                       const float4* __restrict__ b, uint2* __restrict__ ob, size_t nb4,
                       const float4* __restrict__ c, uint2* __restrict__ oc, size_t nc4) {
  size_t stride = (size_t)gridDim.x * 256;
  size_t t0 = (size_t)blockIdx.x * 256 + threadIdx.x;
  for (size_t i = t0; i < na4; i += stride) {
    float4 v = a[i];
    oa[i] = (uint2){pack2(v.x, v.y), pack2(v.z, v.w)};
  }
  for (size_t i = t0; i < nb4; i += stride) {
    float4 v = b[i];
    ob[i] = (uint2){pack2(v.x, v.y), pack2(v.z, v.w)};
  }
  for (size_t i = t0; i < nc4; i += stride) {
    float4 v = c[i];
    oc[i] = (uint2){pack2(v.x, v.y), pack2(v.z, v.w)};
  }
}

// wqkv: [2][1536][512] bf16 (q rows prescaled by 0.125); bqkv: [2][1536] fp32
__global__ void build_qkvw_k(const float4* __restrict__ Wq4, const float4* __restrict__ Wk4,
                             const float4* __restrict__ Wv4, const float* __restrict__ bq,
                             uint2* __restrict__ wqkv4, float* __restrict__ bqkv) {
  const size_t total4 = (size_t)2 * 1536 * 128;  // 128 float4 per 512-col row
  for (size_t idx = (size_t)blockIdx.x * 256 + threadIdx.x; idx < total4; idx += (size_t)gridDim.x * 256) {
    int l = (int)(idx / (1536 * 128));
    int rem = (int)(idx % (1536 * 128));
    int rr = rem >> 7, c4 = rem & 127;
    float4 v;
    if (rr < 512) {
      v = Wq4[(size_t)l * 65536 + rr * 128 + c4];
      v.x *= 0.125f; v.y *= 0.125f; v.z *= 0.125f; v.w *= 0.125f;
    } else if (rr < 1024) {
      v = Wk4[(size_t)l * 65536 + (rr - 512) * 128 + c4];
    } else {
      v = Wv4[(size_t)l * 65536 + (rr - 1024) * 128 + c4];
    }
    wqkv4[idx] = (uint2){pack2(v.x, v.y), pack2(v.z, v.w)};
  }
  for (int i = blockIdx.x * 256 + threadIdx.x; i < 2 * 1536; i += gridDim.x * 256) {
    int l = i / 1536, rr = i % 1536;
    bqkv[i] = (rr < 512) ? bq[l * 512 + rr] * 0.125f : 0.f;
  }
}

__global__ void src_pad_k(const float4* __restrict__ src4, uint2* __restrict__ xb4,
                          int N, int NPAD) {
  size_t total4 = (size_t)NPAD * 128;
  size_t nvalid = (size_t)N * 128;
  for (size_t i = (size_t)blockIdx.x * 256 + threadIdx.x; i < total4; i += (size_t)gridDim.x * 256) {
    uint2 o = {0u, 0u};
    if (i < nvalid) {
      float4 v = src4[i];
      o = (uint2){pack2(v.x, v.y), pack2(v.z, v.w)};
    }
    xb4[i] = o;
  }
}

// ---------- launch ----------
// Folded-BN dataflow (per layer l):
//   QKV(in, Wq')      in = xb (l=0: src_pad; l=1: FF2-l0 pre-BN out); Wq' folded for l=1
//   attn -> aggb
//   Wo(aggb, resid=xb [affine co2 if l=1]) -> tb (pre-BN1), stats bns1
//   wtrans(W1[l], bns1) -> w1p,b1p,co_1l        [replaces bn_apply #1]
//   FF1(tb, w1p, b1p, relu) -> hb
//   FF2(hb, W2[l], resid=tb affine co_1l) -> xb (pre-BN2), stats bns2
//   l=0: wtrans(wqkv[1], bns2) -> wqp,bqp,co2   [replaces bn_apply #2]
//   l=1: bn_ln(xb, bns2) -> out                 [fused final]
extern "C" void kernel_launch(void* const* d_in, const int* in_sizes, int n_in,
                              void* d_out, int out_size, void* d_ws, size_t ws_size,
                              hipStream_t stream)
{
  const float* src = (const float*)d_in[0];
  const int* eidx = (const int*)d_in[1];
  const float* Wq = (const float*)d_in[2];
  const float* bq = (const float*)d_in[3];
  const float* Wk = (const float*)d_in[4];
  const float* Wv = (const float*)d_in[5];
  const float* Wo = (const float*)d_in[6];
  const float* bo = (const float*)d_in[7];
  const float* W1 = (const float*)d_in[8];
  const float* b1 = (const float*)d_in[9];
  const float* W2 = (const float*)d_in[10];
  const float* b2 = (const float*)d_in[11];
  const float* g1 = (const float*)d_in[12];
  const float* be1 = (const float*)d_in[13];
  const float* g2 = (const float*)d_in[14];
  const float* be2 = (const float*)d_in[15];
  const float* lng = (const float*)d_in[16];
  const float* lnb = (const float*)d_in[17];

  const int N = in_sizes[0] / 512;
  const int E = in_sizes[1] / 2;
  const int NPAD = ((N + 1023) / 1024) * 1024;  // m-tiles divisible by 8 (XCD swizzle)
  const int MT = NPAD / 128;
  const int XCHUNK = MT / 8;
  const int NB = (N + 1023) / 1024;             // scan blocks (<= 64)

  char* w = (char*)d_ws;
  size_t off = 0;
  auto alloc = [&](size_t b) -> char* { char* p = w + off; off = (off + b + 255) & ~(size_t)255; return p; };
  unsigned short* qkvb = (unsigned short*)alloc((size_t)NPAD * 1536 * 2);
  unsigned short* aggb = (unsigned short*)alloc((size_t)NPAD * 512 * 2);
  unsigned short* hb   = qkvb;  // FF hidden; qkv/agg dead by then
  unsigned short* xb   = (unsigned short*)alloc((size_t)NPAD * 512 * 2);
  unsigned short* tb   = (unsigned short*)alloc((size_t)NPAD * 512 * 2);  // pre-BN tmp
  unsigned short* wqkv = (unsigned short*)alloc((size_t)2 * 1536 * 512 * 2);
  float* bqkv          = (float*)alloc((size_t)2 * 1536 * 4);
  unsigned short* wWo = (unsigned short*)alloc((size_t)2 * 512 * 512 * 2);
  unsigned short* wW1 = (unsigned short*)alloc((size_t)2 * 2048 * 512 * 2);
  unsigned short* wW2 = (unsigned short*)alloc((size_t)2 * 512 * 2048 * 2);
  unsigned short* w1p = (unsigned short*)alloc((size_t)2048 * 512 * 2);  // folded W1 (per layer)
  float* b1p          = (float*)alloc((size_t)2048 * 4);
  unsigned short* wqp = (unsigned short*)alloc((size_t)1536 * 512 * 2);  // folded Wqkv (layer 1)
  float* bqp          = (float*)alloc((size_t)1536 * 4);
  int* rowptr = (int*)alloc((size_t)(N + 1) * 4);
  int* cursor = (int*)alloc((size_t)N * 4);
  int* deg    = (int*)alloc((size_t)N * 4);
  int* esrc   = (int*)alloc((size_t)E * 4);
  float* bnsum = (float*)alloc(4096 * 4);
  float* co1  = (float*)alloc(1024 * 4);  // BN1 affine, layer 0
  float* co2  = (float*)alloc(1024 * 4);  // BN2 affine, layer 0
  float* co3  = (float*)alloc(1024 * 4);  // BN1 affine, layer 1
  int* bpart  = (int*)alloc(64 * 4);
  int* boff2  = (int*)alloc(64 * 4);
  (void)ws_size; (void)n_in; (void)out_size;

  const int* srci = eidx;
  const int* tgt  = eidx + E;

  hipMemsetAsync(deg, 0, (size_t)N * 4, stream);
  hipMemsetAsync(bnsum, 0, 4096 * 4, stream);

  src_pad_k<<<2048, 256, 0, stream>>>((const float4*)src, (uint2*)xb, N, NPAD);
  build_qkvw_k<<<1024, 256, 0, stream>>>((const float4*)Wq, (const float4*)Wk,
                                         (const float4*)Wv, bq, (uint2*)wqkv, bqkv);
  cvt3_k<<<1024, 256, 0, stream>>>(
      (const float4*)Wo, (uint2*)wWo, (size_t)2 * 512 * 512 / 4,
      (const float4*)W1, (uint2*)wW1, (size_t)2 * 2048 * 512 / 4,
      (const float4*)W2, (uint2*)wW2, (size_t)2 * 512 * 2048 / 4);
  hist_k<<<1250, 256, 0, stream>>>(tgt, deg, E);
  scan1_k<<<NB, 1024, 0, stream>>>(deg, bpart, N);
  scan2_k<<<1, 64, 0, stream>>>(bpart, boff2, rowptr, NB, N);
  scan3_k<<<NB, 1024, 0, stream>>>(deg, boff2, rowptr, cursor, N);
  scatter_k<<<1250, 256, 0, stream>>>(srci, tgt, cursor, esrc, E);

  for (int l = 0; l < 2; l++) {
    const unsigned short* Wo_l = wWo + (size_t)l * 512 * 512;
    const unsigned short* W2_l = wW2 + (size_t)l * 512 * 2048;
    float* bns1 = bnsum + (size_t)(l * 2 + 0) * 1024;
    float* bns2 = bnsum + (size_t)(l * 2 + 1) * 1024;
    float* co_1 = (l == 0) ? co1 : co3;  // BN1 affine for this layer

    // QKV: l=0 original weights; l=1 BN2-folded weights (wqp/bqp)
    const unsigned short* Wq_l = (l == 0) ? wqkv : wqp;
    const float* bq_l = (l == 0) ? bqkv : bqp;
    gemm_bt<<<MT * 12, 256, 0, stream>>>(
        xb, Wq_l, bq_l, 0, nullptr, nullptr, qkvb, nullptr, 0, 1536, 512, 12, XCHUNK);
    attn_k<<<(N + 3) / 4, 256, 0, stream>>>(qkvb, rowptr, esrc, aggb, N);
    // Wo: resid = xb (l=0 plain; l=1 affine-BN2 of pre-BN xb), out tb + BN1 stats
    gemm_bt<<<MT * 4, 256, 0, stream>>>(
        aggb, Wo_l, bo + l * 512, 0, xb, (l == 0) ? nullptr : co2,
        tb, bns1, N, 512, 512, 4, XCHUNK);
    // fold BN1 into W1 (replaces bn_apply): w1p = W1*sa, b1p = b1 + W1.sb
    wtrans_k<<<512, 256, 0, stream>>>(
        wW1 + (size_t)l * 2048 * 512, b1 + l * 2048, bns1,
        g1 + l * 512, be1 + l * 512, N, 2048, w1p, b1p, co_1);
    // FF1: reads pre-BN tb with folded weights
    gemm_bt<<<MT * 16, 256, 0, stream>>>(
        tb, w1p, b1p, 1, nullptr, nullptr, hb, nullptr, 0, 2048, 512, 16, XCHUNK);
    // FF2: resid = BN1(tb) via affine co_1; out xb (pre-BN2) + BN2 stats
    gemm_bt<<<MT * 4, 256, 0, stream>>>(
        hb, W2_l, b2 + l * 512, 0, tb, co_1, xb, bns2, N, 512, 2048, 4, XCHUNK);
    if (l == 0) {
      // fold BN2 into layer-1 QKV weights (replaces bn_apply)
      wtrans_k<<<512, 256, 0, stream>>>(
          wqkv + (size_t)1536 * 512, bqkv + 1536, bns2,
          g2, be2, N, 1536, wqp, bqp, co2);
    } else {
      // final: fused BN2 + LayerNorm on pre-BN xb
      bn_ln_k<<<(N + 3) / 4, 256, 0, stream>>>(
          xb, bns2, g2 + 512, be2 + 512, lng, lnb, (float*)d_out, N);
    }
  }
}

// Round 11
// 810.791 us; speedup vs baseline: 1.1280x; 1.0201x over previous
//
#include <hip/hip_runtime.h>
#include <stdint.h>

typedef __attribute__((ext_vector_type(4))) float f32x4;
typedef __attribute__((ext_vector_type(8))) short bf16x8;

__device__ __forceinline__ float bitsf(unsigned u) {
  union { unsigned u; float f; } x; x.u = u; return x.f;
}
__device__ __forceinline__ float b2f(unsigned short u) { return bitsf(((unsigned)u) << 16); }
__device__ __forceinline__ unsigned short f2b(float f) {
  union { float f; unsigned u; } x; x.f = f;
  unsigned r = x.u + 0x7FFFu + ((x.u >> 16) & 1u);
  return (unsigned short)(r >> 16);
}
__device__ __forceinline__ unsigned pack2(float lo, float hi) {
  return ((unsigned)f2b(hi) << 16) | f2b(lo);
}
__device__ __forceinline__ void async16(const void* g, void* l) {
  __builtin_amdgcn_global_load_lds((const __attribute__((address_space(1))) unsigned*)g,
                                   (__attribute__((address_space(3))) unsigned*)l, 16, 0, 0);
}
__device__ __forceinline__ void unpack8(uint4 u, float* f) {
  f[0] = bitsf(u.x << 16); f[1] = bitsf(u.x & 0xFFFF0000u);
  f[2] = bitsf(u.y << 16); f[3] = bitsf(u.y & 0xFFFF0000u);
  f[4] = bitsf(u.z << 16); f[5] = bitsf(u.z & 0xFFFF0000u);
  f[6] = bitsf(u.w << 16); f[7] = bitsf(u.w & 0xFFFF0000u);
}

// out[m,n] = relu?(acc+bias) (+resid); A: MxK bf16 rm, B: NnxK bf16 rm.
// ROUND-8 PROVEN STRUCTURE (851us total; r10: 827 with BN-fold): BK=64 (32KB
// LDS), 2-barrier per K-step, 8 async16/thread per K-step. Three structure
// rewrites (dbuf r4, small-tile r7, counted-vmcnt r9) all regressed -- this is
// the structure's measured optimum at these shapes. raff: per-column affine on
// the residual load (folded-BN residual paths).
// XCD swizzle: b -> xcd=b&7, slot=b>>3; y = slot % YT, x = xcd*XCHUNK + slot/YT.
// A LDS swizzle: sigmaA(r)=r&7. B: sigmaB(r)=(r>>2)&7 so fragment ni, lane lr
// reads row lr*4+ni -> lane's 4 ni cols consecutive => packed uint2 epilogue.
__global__ __launch_bounds__(256, 3) void gemm_bt(
    const unsigned short* __restrict__ A, const unsigned short* __restrict__ B,
    const float* __restrict__ bias, int relu,
    const unsigned short* __restrict__ residb,
    const float* __restrict__ raff,
    unsigned short* __restrict__ outb,
    float* __restrict__ bns, int statN,
    int Nn, int K, int YT, int XCHUNK)
{
  __shared__ __attribute__((aligned(16))) unsigned short As[128 * 64];
  __shared__ __attribute__((aligned(16))) unsigned short Bs[128 * 64];
  const int b = blockIdx.x;
  const int slot = b >> 3;
  const int m0 = ((b & 7) * XCHUNK + slot / YT) * 128;
  const int n0 = (slot % YT) * 128;
  const int tid = threadIdx.x;
  const int lane = tid & 63;
  const int wave = tid >> 6;
  const int wm = (wave & 1) * 64, wn = (wave >> 1) * 64;
  const int lr = lane & 15, lq = lane >> 4;

  f32x4 acc[4][4];
#pragma unroll
  for (int i = 0; i < 4; i++)
#pragma unroll
    for (int j = 0; j < 4; j++) acc[i][j] = (f32x4){0.f, 0.f, 0.f, 0.f};

  const int rloc = lane >> 3;
  const int rq = rloc >> 2;
  const int gswA = (lane & 7) ^ rloc;
  const int rA = 32 * wave + rloc;
  const unsigned short* gA = A + (size_t)(m0 + rA) * K + gswA * 8;
  const unsigned short* gB0 = B + (size_t)(n0 + rA) * K +      (((lane & 7) ^ ((0 + rq) & 7)) * 8);
  const unsigned short* gB1 = B + (size_t)(n0 + rA + 8) * K +  (((lane & 7) ^ ((2 + rq) & 7)) * 8);
  const unsigned short* gB2 = B + (size_t)(n0 + rA + 16) * K + (((lane & 7) ^ ((4 + rq) & 7)) * 8);
  const unsigned short* gB3 = B + (size_t)(n0 + rA + 24) * K + (((lane & 7) ^ ((6 + rq) & 7)) * 8);
  char* lA = (char*)As + wave * 4096;
  char* lB = (char*)Bs + wave * 4096;
  const int sxa = lr & 7;

  for (int k0 = 0; k0 < K; k0 += 64) {
    async16(gA + k0,          lA);
    async16(gA + 8 * K + k0,  lA + 1024);
    async16(gA + 16 * K + k0, lA + 2048);
    async16(gA + 24 * K + k0, lA + 3072);
    async16(gB0 + k0, lB);
    async16(gB1 + k0, lB + 1024);
    async16(gB2 + k0, lB + 2048);
    async16(gB3 + k0, lB + 3072);
    __syncthreads();

    for (int ks = 0; ks < 2; ks++) {
      const int spos = (((ks << 2) + lq) ^ sxa) << 3;
      bf16x8 af[4], bfr[4];
#pragma unroll
      for (int mi = 0; mi < 4; mi++)
        af[mi] = *(const bf16x8*)&As[(wm + mi * 16 + lr) * 64 + spos];
#pragma unroll
      for (int ni = 0; ni < 4; ni++)
        bfr[ni] = *(const bf16x8*)&Bs[(wn + lr * 4 + ni) * 64 + spos];
#pragma unroll
      for (int mi = 0; mi < 4; mi++)
#pragma unroll
        for (int ni = 0; ni < 4; ni++)
          acc[mi][ni] = __builtin_amdgcn_mfma_f32_16x16x32_bf16(af[mi], bfr[ni], acc[mi][ni], 0, 0, 0);
    }
    __syncthreads();
  }

  float sn[4] = {0, 0, 0, 0}, qn[4] = {0, 0, 0, 0};
  const int gnb = n0 + wn + lr * 4;
  float4 bv = {0.f, 0.f, 0.f, 0.f};
  if (bias) bv = *(const float4*)&bias[gnb];
  float4 ra = {1.f, 1.f, 1.f, 1.f}, rb4 = {0.f, 0.f, 0.f, 0.f};
  if (raff) {
    ra = *(const float4*)&raff[gnb];
    rb4 = *(const float4*)&raff[512 + gnb];
  }
#pragma unroll
  for (int mi = 0; mi < 4; mi++) {
#pragma unroll
    for (int r = 0; r < 4; r++) {
      int gm = m0 + wm + mi * 16 + lq * 4 + r;
      size_t base = (size_t)gm * Nn + gnb;
      float v0 = acc[mi][0][r] + bv.x;
      float v1 = acc[mi][1][r] + bv.y;
      float v2 = acc[mi][2][r] + bv.z;
      float v3 = acc[mi][3][r] + bv.w;
      if (relu) {
        v0 = fmaxf(v0, 0.f); v1 = fmaxf(v1, 0.f);
        v2 = fmaxf(v2, 0.f); v3 = fmaxf(v3, 0.f);
      }
      if (residb) {
        uint2 rb = *(const uint2*)&residb[base];
        if (raff) {
          v0 += bitsf(rb.x << 16) * ra.x + rb4.x;
          v1 += bitsf(rb.x & 0xFFFF0000u) * ra.y + rb4.y;
          v2 += bitsf(rb.y << 16) * ra.z + rb4.z;
          v3 += bitsf(rb.y & 0xFFFF0000u) * ra.w + rb4.w;
        } else {
          v0 += bitsf(rb.x << 16); v1 += bitsf(rb.x & 0xFFFF0000u);
          v2 += bitsf(rb.y << 16); v3 += bitsf(rb.y & 0xFFFF0000u);
        }
      }
      uint2 o;
      o.x = pack2(v0, v1);
      o.y = pack2(v2, v3);
      *(uint2*)&outb[base] = o;
      if (bns && gm < statN) {
        sn[0] += v0; qn[0] += v0 * v0;
        sn[1] += v1; qn[1] += v1 * v1;
        sn[2] += v2; qn[2] += v2 * v2;
        sn[3] += v3; qn[3] += v3 * v3;
      }
    }
  }
  if (bns) {
#pragma unroll
    for (int ni = 0; ni < 4; ni++) {
      float s = sn[ni], q = qn[ni];
      s += __shfl_xor(s, 16, 64); q += __shfl_xor(q, 16, 64);
      s += __shfl_xor(s, 32, 64); q += __shfl_xor(q, 32, 64);
      if (lq == 0) {
        int gn = gnb + ni;
        atomicAdd(&bns[gn], s);
        atomicAdd(&bns[512 + gn], q);
      }
    }
  }
}

// ---------- BN weight-fold: wdst[f][c] = wsrc[f][c]*sa[c];
// bdst[f] = bsrc[f] + sum_c wsrc[f][c]*sb[c]; co = {sa[512], sb[512]}.
__global__ __launch_bounds__(256) void wtrans_k(
    const unsigned short* __restrict__ wsrc, const float* __restrict__ bsrc,
    const float* __restrict__ bns, const float* __restrict__ g,
    const float* __restrict__ be, int N, int F,
    unsigned short* __restrict__ wdst, float* __restrict__ bdst,
    float* __restrict__ co)
{
  __shared__ float ssa[512], ssb[512];
  const float invN = 1.0f / (float)N;
  for (int c = threadIdx.x; c < 512; c += 256) {
    float mu = bns[c] * invN;
    float var = bns[512 + c] * invN - mu * mu;
    float ga = g[c] * rsqrtf(var + 1e-5f);
    ssa[c] = ga;
    ssb[c] = be[c] - mu * ga;
  }
  __syncthreads();
  if (blockIdx.x == 0) {
    for (int c = threadIdx.x; c < 512; c += 256) {
      co[c] = ssa[c];
      co[512 + c] = ssb[c];
    }
  }
  const int lane = threadIdx.x & 63, wv = threadIdx.x >> 6;
  const int c0 = lane * 8;
  for (int f = blockIdx.x * 4 + wv; f < F; f += gridDim.x * 4) {
    bf16x8 wrow = *(const bf16x8*)&wsrc[(size_t)f * 512 + c0];
    float d = 0.f;
    uint4 o;
    float w0 = b2f((unsigned short)wrow[0]), w1 = b2f((unsigned short)wrow[1]);
    float w2 = b2f((unsigned short)wrow[2]), w3 = b2f((unsigned short)wrow[3]);
    float w4 = b2f((unsigned short)wrow[4]), w5 = b2f((unsigned short)wrow[5]);
    float w6 = b2f((unsigned short)wrow[6]), w7 = b2f((unsigned short)wrow[7]);
    d = w0 * ssb[c0] + w1 * ssb[c0 + 1] + w2 * ssb[c0 + 2] + w3 * ssb[c0 + 3]
      + w4 * ssb[c0 + 4] + w5 * ssb[c0 + 5] + w6 * ssb[c0 + 6] + w7 * ssb[c0 + 7];
    o.x = pack2(w0 * ssa[c0],     w1 * ssa[c0 + 1]);
    o.y = pack2(w2 * ssa[c0 + 2], w3 * ssa[c0 + 3]);
    o.z = pack2(w4 * ssa[c0 + 4], w5 * ssa[c0 + 5]);
    o.w = pack2(w6 * ssa[c0 + 6], w7 * ssa[c0 + 7]);
    *(uint4*)&wdst[(size_t)f * 512 + c0] = o;
#pragma unroll
    for (int off = 1; off < 64; off <<= 1) d += __shfl_xor(d, off, 64);
    if (lane == 0) bdst[f] = bsrc[f] + d;
  }
}

// ---------- CSR build ----------
__global__ void hist_k(const int* __restrict__ tgt, int* __restrict__ deg, int E) {
  for (int e = blockIdx.x * 256 + threadIdx.x; e < E; e += gridDim.x * 256)
    atomicAdd(&deg[tgt[e]], 1);
}

// multi-block scan: block sums -> 1-wave scan of partials -> per-block offsets.
__global__ void scan1_k(const int* __restrict__ deg, int* __restrict__ part, int n) {
  __shared__ int ws[16];
  int i = blockIdx.x * 1024 + threadIdx.x;
  int x = (i < n) ? deg[i] : 0;
#pragma unroll
  for (int off = 1; off < 64; off <<= 1) x += __shfl_xor(x, off, 64);
  if ((threadIdx.x & 63) == 0) ws[threadIdx.x >> 6] = x;
  __syncthreads();
  if (threadIdx.x == 0) {
    int s = 0;
#pragma unroll
    for (int j = 0; j < 16; j++) s += ws[j];
    part[blockIdx.x] = s;
  }
}

__global__ void scan2_k(const int* __restrict__ part, int* __restrict__ boff,
                        int* __restrict__ rowptr, int nb, int n) {
  int lane = threadIdx.x;
  int x = (lane < nb) ? part[lane] : 0;
  int v = x;
#pragma unroll
  for (int off = 1; off < 64; off <<= 1) {
    int t = __shfl_up(v, off, 64);
    if (lane >= off) v += t;
  }
  if (lane < nb) boff[lane] = v - x;  // exclusive
  if (lane == 63) rowptr[n] = v;      // grand total
}

__global__ void scan3_k(const int* __restrict__ deg, const int* __restrict__ boff,
                        int* __restrict__ rowptr, int* __restrict__ cursor, int n) {
  __shared__ int ws[16];
  const int lane = threadIdx.x & 63, wid = threadIdx.x >> 6;
  int i = blockIdx.x * 1024 + threadIdx.x;
  int x = (i < n) ? deg[i] : 0;
  int v = x;
#pragma unroll
  for (int off = 1; off < 64; off <<= 1) {
    int t = __shfl_up(v, off, 64);
    if (lane >= off) v += t;
  }
  if (lane == 63) ws[wid] = v;
  __syncthreads();
  if (wid == 0 && lane < 16) {
    int s = ws[lane];
#pragma unroll
    for (int off = 1; off < 16; off <<= 1) {
      int t = __shfl_up(s, off, 64);
      if (lane >= off) s += t;
    }
    ws[lane] = s;
  }
  __syncthreads();
  int pre = boff[blockIdx.x] + (wid ? ws[wid - 1] : 0) + (v - x);
  if (i < n) { rowptr[i] = pre; cursor[i] = pre; }
}

__global__ void scatter_k(const int* __restrict__ srci, const int* __restrict__ tgt,
                          int* __restrict__ cursor, int* __restrict__ esrc, int E) {
  for (int e = blockIdx.x * 256 + threadIdx.x; e < E; e += gridDim.x * 256) {
    int pos = atomicAdd(&cursor[tgt[e]], 1);
    esrc[pos] = srci[e];
  }
}

// ---------- attention: one WAVE per target node; lane covers 8 channels; 8 lanes/head ----
// v4: PERSISTENT WAVES. Grid = 2048 blocks (8/CU, all resident at 64 VGPR /
// 0 LDS); each wave grid-strides over nodes. Fixes the ~34% occupancy from
// one-node-per-wave + Poisson-degree block-retirement imbalance (r10 counters):
// all 32 waves/CU stay resident for the whole kernel, and 2-3 nodes/wave
// average out degree variance. Body unchanged (v3: index cache + 8-edge
// chunks, 16 K/V gathers in flight).
__global__ __launch_bounds__(256) void attn_k(
    const unsigned short* __restrict__ qkv, const int* __restrict__ rowptr,
    const int* __restrict__ esrc, unsigned short* __restrict__ aggb, int N)
{
  const int lane = threadIdx.x & 63;
  const int gw = blockIdx.x * 4 + (threadIdx.x >> 6);
  const int NW = gridDim.x * 4;
  for (int node = gw; node < N; node += NW) {
  const int beg = rowptr[node], end = rowptr[node + 1];
  const uint4* qrow = (const uint4*)(qkv + (size_t)node * 1536);
  float qf[8];
  unpack8(qrow[lane], qf);
  float acc[8] = {0, 0, 0, 0, 0, 0, 0, 0};
  float ssum = 0.f;

  for (int blk = beg; blk < end; blk += 64) {
    const int nb = min(64, end - blk);
    int idxl = esrc[blk + (lane < nb ? lane : 0)];
    int i = 0;
    for (; i + 7 < nb; i += 8) {
      int e0 = __shfl(idxl, i + 0, 64), e1 = __shfl(idxl, i + 1, 64);
      int e2 = __shfl(idxl, i + 2, 64), e3 = __shfl(idxl, i + 3, 64);
      int e4 = __shfl(idxl, i + 4, 64), e5 = __shfl(idxl, i + 5, 64);
      int e6 = __shfl(idxl, i + 6, 64), e7 = __shfl(idxl, i + 7, 64);
      const uint4* b0 = (const uint4*)(qkv + (size_t)e0 * 1536);
      const uint4* b1 = (const uint4*)(qkv + (size_t)e1 * 1536);
      const uint4* b2 = (const uint4*)(qkv + (size_t)e2 * 1536);
      const uint4* b3 = (const uint4*)(qkv + (size_t)e3 * 1536);
      const uint4* b4 = (const uint4*)(qkv + (size_t)e4 * 1536);
      const uint4* b5 = (const uint4*)(qkv + (size_t)e5 * 1536);
      const uint4* b6 = (const uint4*)(qkv + (size_t)e6 * 1536);
      const uint4* b7 = (const uint4*)(qkv + (size_t)e7 * 1536);
      uint4 k0 = b0[64 + lane], k1 = b1[64 + lane], k2 = b2[64 + lane], k3 = b3[64 + lane];
      uint4 k4 = b4[64 + lane], k5 = b5[64 + lane], k6 = b6[64 + lane], k7 = b7[64 + lane];
      uint4 v0 = b0[128 + lane], v1 = b1[128 + lane], v2 = b2[128 + lane], v3 = b3[128 + lane];
      uint4 v4 = b4[128 + lane], v5 = b5[128 + lane], v6 = b6[128 + lane], v7 = b7[128 + lane];
      float kf[8];
      float p0 = 0.f, p1 = 0.f, p2 = 0.f, p3 = 0.f, p4 = 0.f, p5 = 0.f, p6 = 0.f, p7 = 0.f;
      unpack8(k0, kf);
#pragma unroll
      for (int j = 0; j < 8; j++) p0 += qf[j] * kf[j];
      unpack8(k1, kf);
#pragma unroll
      for (int j = 0; j < 8; j++) p1 += qf[j] * kf[j];
      unpack8(k2, kf);
#pragma unroll
      for (int j = 0; j < 8; j++) p2 += qf[j] * kf[j];
      unpack8(k3, kf);
#pragma unroll
      for (int j = 0; j < 8; j++) p3 += qf[j] * kf[j];
      unpack8(k4, kf);
#pragma unroll
      for (int j = 0; j < 8; j++) p4 += qf[j] * kf[j];
      unpack8(k5, kf);
#pragma unroll
      for (int j = 0; j < 8; j++) p5 += qf[j] * kf[j];
      unpack8(k6, kf);
#pragma unroll
      for (int j = 0; j < 8; j++) p6 += qf[j] * kf[j];
      unpack8(k7, kf);
#pragma unroll
      for (int j = 0; j < 8; j++) p7 += qf[j] * kf[j];
#pragma unroll
      for (int off = 1; off < 8; off <<= 1) {
        p0 += __shfl_xor(p0, off, 64); p1 += __shfl_xor(p1, off, 64);
        p2 += __shfl_xor(p2, off, 64); p3 += __shfl_xor(p3, off, 64);
        p4 += __shfl_xor(p4, off, 64); p5 += __shfl_xor(p5, off, 64);
        p6 += __shfl_xor(p6, off, 64); p7 += __shfl_xor(p7, off, 64);
      }
      float w0 = __expf(p0), w1 = __expf(p1), w2 = __expf(p2), w3 = __expf(p3);
      float w4 = __expf(p4), w5 = __expf(p5), w6 = __expf(p6), w7 = __expf(p7);
      ssum += ((w0 + w1) + (w2 + w3)) + ((w4 + w5) + (w6 + w7));
      float vf[8];
      unpack8(v0, vf);
#pragma unroll
      for (int j = 0; j < 8; j++) acc[j] += w0 * vf[j];
      unpack8(v1, vf);
#pragma unroll
      for (int j = 0; j < 8; j++) acc[j] += w1 * vf[j];
      unpack8(v2, vf);
#pragma unroll
      for (int j = 0; j < 8; j++) acc[j] += w2 * vf[j];
      unpack8(v3, vf);
#pragma unroll
      for (int j = 0; j < 8; j++) acc[j] += w3 * vf[j];
      unpack8(v4, vf);
#pragma unroll
      for (int j = 0; j < 8; j++) acc[j] += w4 * vf[j];
      unpack8(v5, vf);
#pragma unroll
      for (int j = 0; j < 8; j++) acc[j] += w5 * vf[j];
      unpack8(v6, vf);
#pragma unroll
      for (int j = 0; j < 8; j++) acc[j] += w6 * vf[j];
      unpack8(v7, vf);
#pragma unroll
      for (int j = 0; j < 8; j++) acc[j] += w7 * vf[j];
    }
    for (; i < nb; i++) {
      int e0 = __shfl(idxl, i, 64);
      const uint4* b0 = (const uint4*)(qkv + (size_t)e0 * 1536);
      uint4 k0 = b0[64 + lane], v0 = b0[128 + lane];
      float kf[8], vf[8];
      unpack8(k0, kf);
      float p0 = 0.f;
#pragma unroll
      for (int j = 0; j < 8; j++) p0 += qf[j] * kf[j];
#pragma unroll
      for (int off = 1; off < 8; off <<= 1) p0 += __shfl_xor(p0, off, 64);
      float w0 = __expf(p0);
      ssum += w0;
      unpack8(v0, vf);
#pragma unroll
      for (int j = 0; j < 8; j++) acc[j] += w0 * vf[j];
    }
  }
  float inv = 1.0f / (ssum + 1e-16f);
  uint4 o;
  o.x = pack2(acc[0] * inv, acc[1] * inv);
  o.y = pack2(acc[2] * inv, acc[3] * inv);
  o.z = pack2(acc[4] * inv, acc[5] * inv);
  o.w = pack2(acc[6] * inv, acc[7] * inv);
  ((uint4*)(aggb + (size_t)node * 512))[lane] = o;
  }
}

// ---------- fused final BN + LayerNorm ----------
__global__ __launch_bounds__(256) void bn_ln_k(
    const unsigned short* __restrict__ tb, const float* __restrict__ bns,
    const float* __restrict__ g, const float* __restrict__ be,
    const float* __restrict__ lng, const float* __restrict__ lnb,
    float* __restrict__ out, int N)
{
  int row = blockIdx.x * 4 + (threadIdx.x >> 6);
  int lane = threadIdx.x & 63;
  if (row >= N) return;
  const int c0 = lane * 8;
  const float invN = 1.0f / (float)N;
  float sa[8], sb[8];
#pragma unroll
  for (int j = 0; j < 8; j++) {
    float mu = bns[c0 + j] * invN;
    float var = bns[512 + c0 + j] * invN - mu * mu;
    float ga = g[c0 + j] * rsqrtf(var + 1e-5f);
    sa[j] = ga;
    sb[j] = be[c0 + j] - mu * ga;
  }
  const uint4* xr = (const uint4*)(tb + (size_t)row * 512);
  float v[8];
  unpack8(xr[lane], v);
#pragma unroll
  for (int j = 0; j < 8; j++) v[j] = v[j] * sa[j] + sb[j];
  float s = 0.f, q = 0.f;
#pragma unroll
  for (int j = 0; j < 8; j++) { s += v[j]; q += v[j] * v[j]; }
#pragma unroll
  for (int off = 32; off > 0; off >>= 1) { s += __shfl_xor(s, off, 64); q += __shfl_xor(q, off, 64); }
  float mu = s * (1.0f / 512.0f);
  float var = q * (1.0f / 512.0f) - mu * mu;
  float inv = rsqrtf(var + 1e-5f);
  float* orow = out + (size_t)row * 512;
#pragma unroll
  for (int j = 0; j < 8; j++)
    orow[c0 + j] = (v[j] - mu) * inv * lng[c0 + j] + lnb[c0 + j];
}

// ---------- conversions (float4-vectorized, G13) ----------
__global__ void cvt3_k(const float4* __restrict__ a, uint2* __restrict__ oa, size_t na4,
                       const float4* __restrict__ b, uint2* __restrict__ ob, size_t nb4,
                       const float4* __restrict__ c, uint2* __restrict__ oc, size_t nc4) {
  size_t stride = (size_t)gridDim.x * 256;
  size_t t0 = (size_t)blockIdx.x * 256 + threadIdx.x;
  for (size_t i = t0; i < na4; i += stride) {
    float4 v = a[i];
    oa[i] = (uint2){pack2(v.x, v.y), pack2(v.z, v.w)};
  }
  for (size_t i = t0; i < nb4; i += stride) {
    float4 v = b[i];
    ob[i] = (uint2){pack2(v.x, v.y), pack2(v.z, v.w)};
  }
  for (size_t i = t0; i < nc4; i += stride) {
    float4 v = c[i];
    oc[i] = (uint2){pack2(v.x, v.y), pack2(v.z, v.w)};
  }
}

// wqkv: [2][1536][512] bf16 (q rows prescaled by 0.125); bqkv: [2][1536] fp32
__global__ void build_qkvw_k(const float4* __restrict__ Wq4, const float4* __restrict__ Wk4,
                             const float4* __restrict__ Wv4, const float* __restrict__ bq,
                             uint2* __restrict__ wqkv4, float* __restrict__ bqkv) {
  const size_t total4 = (size_t)2 * 1536 * 128;  // 128 float4 per 512-col row
  for (size_t idx = (size_t)blockIdx.x * 256 + threadIdx.x; idx < total4; idx += (size_t)gridDim.x * 256) {
    int l = (int)(idx / (1536 * 128));
    int rem = (int)(idx % (1536 * 128));
    int rr = rem >> 7, c4 = rem & 127;
    float4 v;
    if (rr < 512) {
      v = Wq4[(size_t)l * 65536 + rr * 128 + c4];
      v.x *= 0.125f; v.y *= 0.125f; v.z *= 0.125f; v.w *= 0.125f;
    } else if (rr < 1024) {
      v = Wk4[(size_t)l * 65536 + (rr - 512) * 128 + c4];
    } else {
      v = Wv4[(size_t)l * 65536 + (rr - 1024) * 128 + c4];
    }
    wqkv4[idx] = (uint2){pack2(v.x, v.y), pack2(v.z, v.w)};
  }
  for (int i = blockIdx.x * 256 + threadIdx.x; i < 2 * 1536; i += gridDim.x * 256) {
    int l = i / 1536, rr = i % 1536;
    bqkv[i] = (rr < 512) ? bq[l * 512 + rr] * 0.125f : 0.f;
  }
}

__global__ void src_pad_k(const float4* __restrict__ src4, uint2* __restrict__ xb4,
                          int N, int NPAD) {
  size_t total4 = (size_t)NPAD * 128;
  size_t nvalid = (size_t)N * 128;
  for (size_t i = (size_t)blockIdx.x * 256 + threadIdx.x; i < total4; i += (size_t)gridDim.x * 256) {
    uint2 o = {0u, 0u};
    if (i < nvalid) {
      float4 v = src4[i];
      o = (uint2){pack2(v.x, v.y), pack2(v.z, v.w)};
    }
    xb4[i] = o;
  }
}

// ---------- launch ----------
// Folded-BN dataflow (per layer l):
//   QKV(in, Wq')      in = xb (l=0: src_pad; l=1: FF2-l0 pre-BN out); Wq' folded for l=1
//   attn -> aggb
//   Wo(aggb, resid=xb [affine co2 if l=1]) -> tb (pre-BN1), stats bns1
//   wtrans(W1[l], bns1) -> w1p,b1p,co_1l
//   FF1(tb, w1p, b1p, relu) -> hb
//   FF2(hb, W2[l], resid=tb affine co_1l) -> xb (pre-BN2), stats bns2
//   l=0: wtrans(wqkv[1], bns2) -> wqp,bqp,co2
//   l=1: bn_ln(xb, bns2) -> out
extern "C" void kernel_launch(void* const* d_in, const int* in_sizes, int n_in,
                              void* d_out, int out_size, void* d_ws, size_t ws_size,
                              hipStream_t stream)
{
  const float* src = (const float*)d_in[0];
  const int* eidx = (const int*)d_in[1];
  const float* Wq = (const float*)d_in[2];
  const float* bq = (const float*)d_in[3];
  const float* Wk = (const float*)d_in[4];
  const float* Wv = (const float*)d_in[5];
  const float* Wo = (const float*)d_in[6];
  const float* bo = (const float*)d_in[7];
  const float* W1 = (const float*)d_in[8];
  const float* b1 = (const float*)d_in[9];
  const float* W2 = (const float*)d_in[10];
  const float* b2 = (const float*)d_in[11];
  const float* g1 = (const float*)d_in[12];
  const float* be1 = (const float*)d_in[13];
  const float* g2 = (const float*)d_in[14];
  const float* be2 = (const float*)d_in[15];
  const float* lng = (const float*)d_in[16];
  const float* lnb = (const float*)d_in[17];

  const int N = in_sizes[0] / 512;
  const int E = in_sizes[1] / 2;
  const int NPAD = ((N + 1023) / 1024) * 1024;  // m-tiles divisible by 8 (XCD swizzle)
  const int MT = NPAD / 128;
  const int XCHUNK = MT / 8;
  const int NB = (N + 1023) / 1024;             // scan blocks (<= 64)

  char* w = (char*)d_ws;
  size_t off = 0;
  auto alloc = [&](size_t b) -> char* { char* p = w + off; off = (off + b + 255) & ~(size_t)255; return p; };
  unsigned short* qkvb = (unsigned short*)alloc((size_t)NPAD * 1536 * 2);
  unsigned short* aggb = (unsigned short*)alloc((size_t)NPAD * 512 * 2);
  unsigned short* hb   = qkvb;  // FF hidden; qkv/agg dead by then
  unsigned short* xb   = (unsigned short*)alloc((size_t)NPAD * 512 * 2);
  unsigned short* tb   = (unsigned short*)alloc((size_t)NPAD * 512 * 2);  // pre-BN tmp
  unsigned short* wqkv = (unsigned short*)alloc((size_t)2 * 1536 * 512 * 2);
  float* bqkv          = (float*)alloc((size_t)2 * 1536 * 4);
  unsigned short* wWo = (unsigned short*)alloc((size_t)2 * 512 * 512 * 2);
  unsigned short* wW1 = (unsigned short*)alloc((size_t)2 * 2048 * 512 * 2);
  unsigned short* wW2 = (unsigned short*)alloc((size_t)2 * 512 * 2048 * 2);
  unsigned short* w1p = (unsigned short*)alloc((size_t)2048 * 512 * 2);  // folded W1 (per layer)
  float* b1p          = (float*)alloc((size_t)2048 * 4);
  unsigned short* wqp = (unsigned short*)alloc((size_t)1536 * 512 * 2);  // folded Wqkv (layer 1)
  float* bqp          = (float*)alloc((size_t)1536 * 4);
  int* rowptr = (int*)alloc((size_t)(N + 1) * 4);
  int* cursor = (int*)alloc((size_t)N * 4);
  int* deg    = (int*)alloc((size_t)N * 4);
  int* esrc   = (int*)alloc((size_t)E * 4);
  float* bnsum = (float*)alloc(4096 * 4);
  float* co1  = (float*)alloc(1024 * 4);  // BN1 affine, layer 0
  float* co2  = (float*)alloc(1024 * 4);  // BN2 affine, layer 0
  float* co3  = (float*)alloc(1024 * 4);  // BN1 affine, layer 1
  int* bpart  = (int*)alloc(64 * 4);
  int* boff2  = (int*)alloc(64 * 4);
  (void)ws_size; (void)n_in; (void)out_size;

  const int* srci = eidx;
  const int* tgt  = eidx + E;

  hipMemsetAsync(deg, 0, (size_t)N * 4, stream);
  hipMemsetAsync(bnsum, 0, 4096 * 4, stream);

  src_pad_k<<<2048, 256, 0, stream>>>((const float4*)src, (uint2*)xb, N, NPAD);
  build_qkvw_k<<<1024, 256, 0, stream>>>((const float4*)Wq, (const float4*)Wk,
                                         (const float4*)Wv, bq, (uint2*)wqkv, bqkv);
  cvt3_k<<<1024, 256, 0, stream>>>(
      (const float4*)Wo, (uint2*)wWo, (size_t)2 * 512 * 512 / 4,
      (const float4*)W1, (uint2*)wW1, (size_t)2 * 2048 * 512 / 4,
      (const float4*)W2, (uint2*)wW2, (size_t)2 * 512 * 2048 / 4);
  hist_k<<<1250, 256, 0, stream>>>(tgt, deg, E);
  scan1_k<<<NB, 1024, 0, stream>>>(deg, bpart, N);
  scan2_k<<<1, 64, 0, stream>>>(bpart, boff2, rowptr, NB, N);
  scan3_k<<<NB, 1024, 0, stream>>>(deg, boff2, rowptr, cursor, N);
  scatter_k<<<1250, 256, 0, stream>>>(srci, tgt, cursor, esrc, E);

  for (int l = 0; l < 2; l++) {
    const unsigned short* Wo_l = wWo + (size_t)l * 512 * 512;
    const unsigned short* W2_l = wW2 + (size_t)l * 512 * 2048;
    float* bns1 = bnsum + (size_t)(l * 2 + 0) * 1024;
    float* bns2 = bnsum + (size_t)(l * 2 + 1) * 1024;
    float* co_1 = (l == 0) ? co1 : co3;  // BN1 affine for this layer

    // QKV: l=0 original weights; l=1 BN2-folded weights (wqp/bqp)
    const unsigned short* Wq_l = (l == 0) ? wqkv : wqp;
    const float* bq_l = (l == 0) ? bqkv : bqp;
    gemm_bt<<<MT * 12, 256, 0, stream>>>(
        xb, Wq_l, bq_l, 0, nullptr, nullptr, qkvb, nullptr, 0, 1536, 512, 12, XCHUNK);
    attn_k<<<2048, 256, 0, stream>>>(qkvb, rowptr, esrc, aggb, N);
    // Wo: resid = xb (l=0 plain; l=1 affine-BN2 of pre-BN xb), out tb + BN1 stats
    gemm_bt<<<MT * 4, 256, 0, stream>>>(
        aggb, Wo_l, bo + l * 512, 0, xb, (l == 0) ? nullptr : co2,
        tb, bns1, N, 512, 512, 4, XCHUNK);
    // fold BN1 into W1: w1p = W1*sa, b1p = b1 + W1.sb
    wtrans_k<<<512, 256, 0, stream>>>(
        wW1 + (size_t)l * 2048 * 512, b1 + l * 2048, bns1,
        g1 + l * 512, be1 + l * 512, N, 2048, w1p, b1p, co_1);
    // FF1: reads pre-BN tb with folded weights
    gemm_bt<<<MT * 16, 256, 0, stream>>>(
        tb, w1p, b1p, 1, nullptr, nullptr, hb, nullptr, 0, 2048, 512, 16, XCHUNK);
    // FF2: resid = BN1(tb) via affine co_1; out xb (pre-BN2) + BN2 stats
    gemm_bt<<<MT * 4, 256, 0, stream>>>(
        hb, W2_l, b2 + l * 512, 0, tb, co_1, xb, bns2, N, 512, 2048, 4, XCHUNK);
    if (l == 0) {
      // fold BN2 into layer-1 QKV weights
      wtrans_k<<<512, 256, 0, stream>>>(
          wqkv + (size_t)1536 * 512, bqkv + 1536, bns2,
          g2, be2, N, 1536, wqp, bqp, co2);
    } else {
      // final: fused BN2 + LayerNorm on pre-BN xb
      bn_ln_k<<<(N + 3) / 4, 256, 0, stream>>>(
          xb, bns2, g2 + 512, be2 + 512, lng, lnb, (float*)d_out, N);
    }
  }
}